// Round 5
// baseline (383839.697 us; speedup 1.0000x reference)
//
#include <hip/hip_runtime.h>
#include <math.h>

#define NB 32
#define TIN 512
#define TOUT 512
#define NENC 512
#define NATT 128
#define NU 1024
#define NG 4096
#define NPRE 256
#define NMEL 80
#define NBLK 256
#define NTHR 512

// ws offsets (floats)
#define WS_AH    0u
#define WS_AC    32768u
#define WS_DH    65536u
#define WS_DC    98304u
#define WS_ACTX  131072u
#define WS_AW    147456u
#define WS_AWCUM 163840u
#define WS_PQ    196608u
#define WS_BAR   200704u                    // 512 uints
#define WS_ZA    201216u                    // 32*4096
#define WS_ZD    332288u                    // 32*4096
#define WS_PM    463360u                    // 32*128*512 (transposed [b][a][t])
#define WS_PRE   2560512u                   // 512*32*256
#define WS_ZERO_BYTES (WS_ZA * 4u)
#define OUT_ALIGN ((size_t)NB * NMEL * TOUT + (size_t)NB * TOUT)

__device__ __forceinline__ float fsigm(float x) { return 1.f / (1.f + __expf(-x)); }
__device__ __forceinline__ float ftanh(float x) { return 1.f - 2.f / (__expf(2.f * x) + 1.f); }

// ---------------- setup kernels ----------------
__global__ __launch_bounds__(256) void prenet1_kernel(const float* __restrict__ dec,
                                                      const float* __restrict__ w1,
                                                      float* __restrict__ pre) {
    int t = blockIdx.x;
    __shared__ float xl[NB][NMEL];
    for (int i = threadIdx.x; i < NB * NMEL; i += 256) {
        int b = i / NMEL, m = i % NMEL;
        xl[b][m] = (t == 0) ? 0.0f : dec[(b * NMEL + m) * TOUT + (t - 1)];
    }
    __syncthreads();
    int j = threadIdx.x;
    float acc[NB];
#pragma unroll
    for (int b = 0; b < NB; b++) acc[b] = 0.0f;
    for (int m = 0; m < NMEL; m++) {
        float w = w1[j * NMEL + m];
#pragma unroll
        for (int b = 0; b < NB; b++) acc[b] += xl[b][m] * w;
    }
    for (int b = 0; b < NB; b++) pre[((size_t)t * NB + b) * NPRE + j] = fmaxf(acc[b], 0.0f);
}

__global__ __launch_bounds__(256) void prenet2_kernel(const float* __restrict__ w2,
                                                      float* __restrict__ pre) {
    int t = blockIdx.x;
    __shared__ float hl[NB][NPRE];
    for (int i = threadIdx.x; i < NB * NPRE; i += 256)
        hl[i / NPRE][i % NPRE] = pre[(size_t)t * NB * NPRE + i];
    __syncthreads();
    int j = threadIdx.x;
    float acc[NB];
#pragma unroll
    for (int b = 0; b < NB; b++) acc[b] = 0.0f;
    for (int k = 0; k < NPRE; k++) {
        float w = w2[j * NPRE + k];
#pragma unroll
        for (int b = 0; b < NB; b++) acc[b] += hl[b][k] * w;
    }
    for (int b = 0; b < NB; b++) pre[((size_t)t * NB + b) * NPRE + j] = fmaxf(acc[b], 0.0f);
}

// processed_memory TRANSPOSED: pmt[b][a][t]
__global__ __launch_bounds__(128) void pmt_kernel(const float* __restrict__ mem,
                                                  const float* __restrict__ mw,
                                                  float* __restrict__ pmt) {
    int b = blockIdx.y, t0 = blockIdx.x * 4;
    __shared__ float ml[4][NENC];
    for (int i = threadIdx.x; i < 4 * NENC; i += 128)
        ml[i / NENC][i % NENC] = mem[((size_t)b * TIN + t0 + i / NENC) * NENC + (i % NENC)];
    __syncthreads();
    int a = threadIdx.x;
    float acc[4] = {0, 0, 0, 0};
    for (int e = 0; e < NENC; e++) {
        float w = mw[a * NENC + e];
#pragma unroll
        for (int tt = 0; tt < 4; tt++) acc[tt] += ml[tt][e] * w;
    }
    *(float4*)&pmt[((size_t)b * NATT + a) * TIN + t0] = make_float4(acc[0], acc[1], acc[2], acc[3]);
}

// ---------------- persistent kernel ----------------
struct Params {
    const float* memory; const int* mlen;
    const float* awih; const float* awhh; const float* abih; const float* abhh;
    const float* qw; const float* vw; const float* wc; const float* ldw;
    const float* dwih; const float* dwhh; const float* dbih; const float* dbhh;
    const float* pjw; const float* pjb; const float* gtw; const float* gtb;
    float* ws; float* out;
};

// hardened monotone two-level grid barrier; spin mixes acquire-loads with
// periodic fetch_add(0) RMW (RMW is served at the coherence point -> cannot
// observe a stale value forever). Counters never reset mid-run.
__device__ __forceinline__ void gbar(unsigned* bar, unsigned n) {
    __syncthreads();
    if (threadIdx.x == 0) {
        __threadfence();
        unsigned* grp  = bar + ((blockIdx.x >> 5) << 5);  // 8 groups, 128B apart
        unsigned* root = bar + 256;
        unsigned old = __hip_atomic_fetch_add(grp, 1u, __ATOMIC_ACQ_REL, __HIP_MEMORY_SCOPE_AGENT);
        if (old + 1u == (n << 5))
            __hip_atomic_fetch_add(root, 1u, __ATOMIC_ACQ_REL, __HIP_MEMORY_SCOPE_AGENT);
        unsigned spins = 0;
        for (;;) {
            unsigned r;
            if ((++spins & 31u) != 0u)
                r = __hip_atomic_load(root, __ATOMIC_ACQUIRE, __HIP_MEMORY_SCOPE_AGENT);
            else
                r = __hip_atomic_fetch_add(root, 0u, __ATOMIC_ACQUIRE, __HIP_MEMORY_SCOPE_AGENT);
            if (r >= (n << 3)) break;
            __builtin_amdgcn_s_sleep(4);
        }
        __threadfence();
    }
    __syncthreads();
}

// ---- z GEMV: wave handles 2 cols; lane = (col: lane>>5, kpos: lane&31) ----
__device__ __forceinline__ void zreg128(const float* __restrict__ w,
                                        const float* __restrict__ x, int xs,
                                        int nticks, int kpos, float* acc) {
    for (int tk = 0; tk < nticks; ++tk) {
        int k = tk * 128 + kpos * 4;
        float4 w4 = *(const float4*)(w + k);
#pragma unroll
        for (int b = 0; b < NB; ++b) {
            float4 x4 = *(const float4*)(x + (size_t)b * xs + k);
            acc[b] = fmaf(w4.x, x4.x, acc[b]);
            acc[b] = fmaf(w4.y, x4.y, acc[b]);
            acc[b] = fmaf(w4.z, x4.z, acc[b]);
            acc[b] = fmaf(w4.w, x4.w, acc[b]);
        }
    }
}

// 4 cols/wave variant for K=512 (lane = col: lane>>4, kpos: lane&15)
__device__ __forceinline__ void zreg64(const float* __restrict__ w,
                                       const float* __restrict__ x, int xs,
                                       int nticks, int kpos, float* acc) {
    for (int tk = 0; tk < nticks; ++tk) {
        int k = tk * 64 + kpos * 4;
        float4 w4 = *(const float4*)(w + k);
#pragma unroll
        for (int b = 0; b < NB; ++b) {
            float4 x4 = *(const float4*)(x + (size_t)b * xs + k);
            acc[b] = fmaf(w4.x, x4.x, acc[b]);
            acc[b] = fmaf(w4.y, x4.y, acc[b]);
            acc[b] = fmaf(w4.z, x4.z, acc[b]);
            acc[b] = fmaf(w4.w, x4.w, acc[b]);
        }
    }
}

// main z item (16 cols): w<256 -> zd(t): dwih[:,:1024]@AH + dwhh@DH
//                        w>=256 -> za(ts): awih[:,:256]@PRE(ts) + awhh@AH
__device__ void z_main_item(const Params& p, int w, int ts, int tid) {
    int wv = tid >> 6, lane = tid & 63, colh = lane >> 5, kpos = lane & 31;
    float* ws = p.ws;
    float acc[NB];
#pragma unroll
    for (int b = 0; b < NB; ++b) acc[b] = 0.f;
    int gcol;
    float* zout;
    if (w < 256) {
        gcol = w * 16 + wv * 2 + colh;
        zreg128(p.dwih + (size_t)gcol * 1536, ws + WS_AH, NU, 8, kpos, acc);
        zreg128(p.dwhh + (size_t)gcol * NU, ws + WS_DH, NU, 8, kpos, acc);
        zout = ws + WS_ZD;
    } else {
        gcol = (w - 256) * 16 + wv * 2 + colh;
        zreg128(p.awih + (size_t)gcol * 768, ws + WS_PRE + (size_t)ts * NB * NPRE, NPRE, 2, kpos, acc);
        zreg128(p.awhh + (size_t)gcol * NU, ws + WS_AH, NU, 8, kpos, acc);
        zout = ws + WS_ZA;
    }
#pragma unroll
    for (int sh = 1; sh <= 16; sh <<= 1) {
#pragma unroll
        for (int b = 0; b < NB; ++b) acc[b] += __shfl_xor(acc[b], sh);
    }
    if (kpos == 0) {
#pragma unroll
        for (int b = 0; b < NB; ++b) zout[((size_t)b << 12) + gcol] = acc[b];
    }
}

// actx z item (32 cols): w<128 -> zd += dwih[:,1024:1536]@ACTX
//                        w>=128 -> za += awih[:,256:768]@ACTX
__device__ void z_actx_item(const Params& p, int w, int tid) {
    int wv = tid >> 6, lane = tid & 63, col4 = lane >> 4, kpos = lane & 15;
    float* ws = p.ws;
    float acc[NB];
#pragma unroll
    for (int b = 0; b < NB; ++b) acc[b] = 0.f;
    int gcol; const float* W; float* zout;
    if (w < 128) {
        gcol = w * 32 + wv * 4 + col4;
        W = p.dwih + (size_t)gcol * 1536 + 1024;
        zout = ws + WS_ZD;
    } else {
        gcol = (w - 128) * 32 + wv * 4 + col4;
        W = p.awih + (size_t)gcol * 768 + 256;
        zout = ws + WS_ZA;
    }
    zreg64(W, ws + WS_ACTX, NENC, 8, kpos, acc);
#pragma unroll
    for (int sh = 1; sh <= 8; sh <<= 1) {
#pragma unroll
        for (int b = 0; b < NB; ++b) acc[b] += __shfl_xor(acc[b], sh);
    }
    if (kpos == 0) {
#pragma unroll
        for (int b = 0; b < NB; ++b) zout[((size_t)b << 12) + gcol] += acc[b];
    }
}

// attn: per b, all 512 t: conv31 -> dense -> tanh -> vdot -> mask -> softmax -> aw
__device__ void attn_block(const Params& p, int b, int step, int tid, float* sm) {
    float* ws = p.ws;
    float* awl = sm, *cuml = sm + 512, *pql = sm + 1024, *red = sm + 1152;
    awl[tid] = ws[WS_AW + b * 512 + tid];
    cuml[tid] = ws[WS_AWCUM + b * 512 + tid];
    if (tid < NATT) pql[tid] = ws[WS_PQ + b * NATT + tid];
    __syncthreads();
    int t = tid;
    float loc[32];
#pragma unroll
    for (int f = 0; f < 32; ++f) loc[f] = 0.f;
    for (int d = 0; d < 31; ++d) {
        int tp = t + d - 15;
        int tc = min(max(tp, 0), 511);
        bool ok = (tp >= 0) && (tp < 512);
        float a_ = ok ? awl[tc] : 0.f;
        float c_ = ok ? cuml[tc] : 0.f;
#pragma unroll
        for (int f = 0; f < 32; ++f)
            loc[f] = fmaf(a_, p.wc[f * 62 + d], fmaf(c_, p.wc[f * 62 + 31 + d], loc[f]));
    }
    float e = 0.f;
    const float* pmt = ws + WS_PM + (size_t)b * NATT * TIN + t;
    for (int a = 0; a < NATT; ++a) {
        float s = pql[a] + pmt[(size_t)a * TIN];
#pragma unroll
        for (int f = 0; f < 32; ++f) s = fmaf(loc[f], p.ldw[a * 32 + f], s);
        e = fmaf(ftanh(s), p.vw[a], e);
    }
    if (t >= p.mlen[b]) e = -3.0e38f;
    float m = e;
#pragma unroll
    for (int sh = 1; sh <= 32; sh <<= 1) m = fmaxf(m, __shfl_xor(m, sh));
    if ((tid & 63) == 0) red[tid >> 6] = m;
    __syncthreads();
    m = fmaxf(fmaxf(fmaxf(red[0], red[1]), fmaxf(red[2], red[3])),
              fmaxf(fmaxf(red[4], red[5]), fmaxf(red[6], red[7])));
    float pv = __expf(e - m);
    float ss = pv;
#pragma unroll
    for (int sh = 1; sh <= 32; sh <<= 1) ss += __shfl_xor(ss, sh);
    if ((tid & 63) == 0) red[8 + (tid >> 6)] = ss;
    __syncthreads();
    float tot = red[8] + red[9] + red[10] + red[11] + red[12] + red[13] + red[14] + red[15];
    float aw = pv / tot;
    ws[WS_AW + b * 512 + t] = aw;
    ws[WS_AWCUM + b * 512 + t] += aw;
    p.out[OUT_ALIGN + ((size_t)b * TOUT + step) * TIN + t] = aw;
}

// ctx: (b, e-quarter): actx[b][e] = sum_t aw[t] * memory[b][t][e]
__device__ void ctx_block(const Params& p, int bid, int tid, float* sm) {
    int b = bid >> 2, q = bid & 3;
    float* ws = p.ws;
    float* awl = sm; float* part = sm + 512;
    awl[tid] = ws[WS_AW + b * 512 + tid];
    __syncthreads();
    int e = tid & 127, tq = tid >> 7;
    const float* mb = p.memory + (size_t)b * TIN * NENC + q * 128 + e;
    float acc = 0.f;
    for (int t = tq * 128; t < tq * 128 + 128; ++t)
        acc = fmaf(awl[t], mb[(size_t)t * NENC], acc);
    part[tq * 128 + e] = acc;
    __syncthreads();
    if (tid < 128)
        ws[WS_ACTX + b * NENC + q * 128 + tid] =
            part[tid] + part[128 + tid] + part[256 + tid] + part[384 + tid];
}

__device__ void agates_pq(const Params& p, int b, int tid, float* sm) {
    float* ahl = sm;
    float* ws = p.ws;
    float* AH = ws + WS_AH + (size_t)b * NU;
    float* AC = ws + WS_AC + (size_t)b * NU;
    const float* Z = ws + WS_ZA + (size_t)b * NG;
    for (int u = tid; u < NU; u += NTHR) {
        float zi = Z[u]          + p.abih[u]          + p.abhh[u];
        float zf = Z[NU + u]     + p.abih[NU + u]     + p.abhh[NU + u];
        float zg = Z[2 * NU + u] + p.abih[2 * NU + u] + p.abhh[2 * NU + u];
        float zo = Z[3 * NU + u] + p.abih[3 * NU + u] + p.abhh[3 * NU + u];
        float c = fsigm(zf) * AC[u] + fsigm(zi) * ftanh(zg);
        float h = fsigm(zo) * ftanh(c);
        AC[u] = c; AH[u] = h; ahl[u] = h;
    }
    __syncthreads();
    int a = tid >> 2, q = tid & 3;
    const float* qr = p.qw + (size_t)a * NU + q * 256;
    const float* h4 = ahl + q * 256;
    float s = 0.f;
#pragma unroll
    for (int k4 = 0; k4 < 64; k4++) {
        float4 hv = *(const float4*)(h4 + k4 * 4);
        float4 wv = *(const float4*)(qr + k4 * 4);
        s = fmaf(hv.x, wv.x, s); s = fmaf(hv.y, wv.y, s);
        s = fmaf(hv.z, wv.z, s); s = fmaf(hv.w, wv.w, s);
    }
    s += __shfl_xor(s, 1); s += __shfl_xor(s, 2);
    if (q == 0) ws[WS_PQ + b * NATT + a] = s;
    __syncthreads();
}

__device__ void dgates_proj(const Params& p, int b, int t, int tid, float* sm) {
    float* dhc = sm;
    float* ws = p.ws;
    float* DH = ws + WS_DH + (size_t)b * NU;
    float* DC = ws + WS_DC + (size_t)b * NU;
    const float* Z = ws + WS_ZD + (size_t)b * NG;
    for (int u = tid; u < NU; u += NTHR) {
        float zi = Z[u]          + p.dbih[u]          + p.dbhh[u];
        float zf = Z[NU + u]     + p.dbih[NU + u]     + p.dbhh[NU + u];
        float zg = Z[2 * NU + u] + p.dbih[2 * NU + u] + p.dbhh[2 * NU + u];
        float zo = Z[3 * NU + u] + p.dbih[3 * NU + u] + p.dbhh[3 * NU + u];
        float c = fsigm(zf) * DC[u] + fsigm(zi) * ftanh(zg);
        float h = fsigm(zo) * ftanh(c);
        DC[u] = c; DH[u] = h; dhc[u] = h;
    }
    for (int i = tid; i < NENC; i += NTHR) dhc[NU + i] = ws[WS_ACTX + b * NENC + i];
    __syncthreads();
    int col = tid >> 2, q = tid & 3;
    if (col < 81) {
        const float* wr = (col < 80) ? (p.pjw + (size_t)col * 1536) : p.gtw;
        const float* d4 = dhc + q * 384;
        const float* w4 = wr + q * 384;
        float s = 0.f;
#pragma unroll
        for (int k4 = 0; k4 < 96; k4++) {
            float4 hv = *(const float4*)(d4 + k4 * 4);
            float4 wv = *(const float4*)(w4 + k4 * 4);
            s = fmaf(hv.x, wv.x, s); s = fmaf(hv.y, wv.y, s);
            s = fmaf(hv.z, wv.z, s); s = fmaf(hv.w, wv.w, s);
        }
        s += __shfl_xor(s, 1); s += __shfl_xor(s, 2);
        if (q == 0) {
            s += (col < 80) ? p.pjb[col] : p.gtb[0];
            if (col < 80) p.out[((size_t)b * NMEL + col) * TOUT + t] = s;
            else          p.out[(size_t)NB * NMEL * TOUT + (size_t)b * TOUT + t] = s;
        }
    }
    __syncthreads();
}

__global__ __launch_bounds__(NTHR, 2) void persist_kernel(Params p) {
    __shared__ float sm[1664];
    int tid = threadIdx.x, bid = blockIdx.x;
    unsigned* bar = (unsigned*)(p.ws + WS_BAR);
    unsigned nb_ = 0;

    // prologue: z_a(0) main part (actx(-1)=0 -> skip actx part), then gates_a(0)+pq(0)
    for (int w = bid; w < 256; w += NBLK) z_main_item(p, 256 + w, 0, tid);
    ++nb_; gbar(bar, nb_);
    if (bid >= 32 && bid < 64) agates_pq(p, bid - 32, tid, sm);
    ++nb_; gbar(bar, nb_);

    for (int t = 0; t < TOUT; ++t) {
        // P1: attn(t) [32] || z-main: zd(t) + za(t+1) [224]
        if (bid < 32) attn_block(p, bid, t, tid, sm);
        else {
            for (int w = bid - 32; w < 512; w += (NBLK - 32)) {
                if (w < 256) z_main_item(p, w, 0, tid);
                else if (t + 1 < TOUT) z_main_item(p, w, t + 1, tid);
            }
        }
        ++nb_; gbar(bar, nb_);
        // P2: ctx(t) [128]
        if (bid < 128) ctx_block(p, bid, tid, sm);
        ++nb_; gbar(bar, nb_);
        // P3: z-actx: zd(t) + za(t+1) [256 items / 256 blocks]
        {
            int w = bid;
            if (w < 128 || t + 1 < TOUT) z_actx_item(p, w, tid);
        }
        ++nb_; gbar(bar, nb_);
        // P4: dgates+proj(t) [32] || agates+pq(t+1) [32]
        if (bid < 32) dgates_proj(p, bid, t, tid, sm);
        else if (bid < 64 && t + 1 < TOUT) agates_pq(p, bid - 32, tid, sm);
        ++nb_; gbar(bar, nb_);
    }

    // self-reset barrier counters (safe: done==NBLK proves nobody still spins)
    if (tid == 0) {
        unsigned* done = bar + 288;
        unsigned old = __hip_atomic_fetch_add(done, 1u, __ATOMIC_ACQ_REL, __HIP_MEMORY_SCOPE_AGENT);
        if (old == NBLK - 1u) {
#pragma unroll
            for (int i = 0; i < 8; ++i)
                __hip_atomic_store(bar + i * 32, 0u, __ATOMIC_RELAXED, __HIP_MEMORY_SCOPE_AGENT);
            __hip_atomic_store(bar + 256, 0u, __ATOMIC_RELAXED, __HIP_MEMORY_SCOPE_AGENT);
            __hip_atomic_store(bar + 288, 0u, __ATOMIC_RELAXED, __HIP_MEMORY_SCOPE_AGENT);
        }
    }
}

extern "C" void kernel_launch(void* const* d_in, const int* in_sizes, int n_in,
                              void* d_out, int out_size, void* d_ws, size_t ws_size,
                              hipStream_t stream) {
    const float* memory = (const float*)d_in[0];
    const float* dec    = (const float*)d_in[1];
    const int*   mlen   = (const int*)d_in[2];
    const float* pw1    = (const float*)d_in[3];
    const float* pw2    = (const float*)d_in[4];
    const float* awih   = (const float*)d_in[5];
    const float* awhh   = (const float*)d_in[6];
    const float* abih   = (const float*)d_in[7];
    const float* abhh   = (const float*)d_in[8];
    const float* qw     = (const float*)d_in[9];
    const float* mw     = (const float*)d_in[10];
    const float* vw     = (const float*)d_in[11];
    const float* wc     = (const float*)d_in[12];
    const float* ldw    = (const float*)d_in[13];
    const float* dwih   = (const float*)d_in[14];
    const float* dwhh   = (const float*)d_in[15];
    const float* dbih   = (const float*)d_in[16];
    const float* dbhh   = (const float*)d_in[17];
    const float* pjw    = (const float*)d_in[18];
    const float* pjb    = (const float*)d_in[19];
    const float* gtw    = (const float*)d_in[20];
    const float* gtb    = (const float*)d_in[21];
    float* ws  = (float*)d_ws;
    float* out = (float*)d_out;

    hipMemsetAsync(d_ws, 0, WS_ZERO_BYTES, stream);
    prenet1_kernel<<<TOUT, 256, 0, stream>>>(dec, pw1, ws + WS_PRE);
    prenet2_kernel<<<TOUT, 256, 0, stream>>>(pw2, ws + WS_PRE);
    pmt_kernel<<<dim3(TIN / 4, NB), 128, 0, stream>>>(memory, mw, ws + WS_PM);

    Params pp = { memory, mlen, awih, awhh, abih, abhh, qw, vw, wc, ldw,
                  dwih, dwhh, dbih, dbhh, pjw, pjb, gtw, gtb, ws, out };
    void* args[] = { &pp };
    hipLaunchCooperativeKernel((const void*)persist_kernel, dim3(NBLK), dim3(NTHR),
                               args, 0, stream);
}

// Round 6
// 192892.200 us; speedup vs baseline: 1.9899x; 1.9899x over previous
//
#include <hip/hip_runtime.h>
#include <math.h>

#define NB 32
#define TIN 512
#define TOUT 512
#define NENC 512
#define NATT 128
#define NU 1024
#define NG 4096
#define NPRE 256
#define NMEL 80
#define NBLK 256
#define NTHR 512

// ws offsets (floats)
#define WS_AH    0u
#define WS_AC    32768u
#define WS_DH    65536u
#define WS_DC    98304u
#define WS_ACTX  131072u
#define WS_AW    147456u
#define WS_AWCUM 163840u
#define WS_PQ    196608u
#define WS_BAR   200704u                    // 512 uints
#define WS_ZA    201216u                    // 32*4096
#define WS_ZD    332288u                    // 32*4096
#define WS_PM    463360u                    // 32*128*512 (transposed [b][a][t])
#define WS_PRE   2560512u                   // 512*32*256
#define WS_ZERO_BYTES (WS_ZA * 4u)
#define OUT_ALIGN ((size_t)NB * NMEL * TOUT + (size_t)NB * TOUT)

__device__ __forceinline__ float fsigm(float x) { return 1.f / (1.f + __expf(-x)); }
__device__ __forceinline__ float ftanh(float x) { return 1.f - 2.f / (__expf(2.f * x) + 1.f); }

// ---------------- setup kernels ----------------
__global__ __launch_bounds__(256) void prenet1_kernel(const float* __restrict__ dec,
                                                      const float* __restrict__ w1,
                                                      float* __restrict__ pre) {
    int t = blockIdx.x;
    __shared__ float xl[NB][NMEL];
    for (int i = threadIdx.x; i < NB * NMEL; i += 256) {
        int b = i / NMEL, m = i % NMEL;
        xl[b][m] = (t == 0) ? 0.0f : dec[(b * NMEL + m) * TOUT + (t - 1)];
    }
    __syncthreads();
    int j = threadIdx.x;
    float acc[NB];
#pragma unroll
    for (int b = 0; b < NB; b++) acc[b] = 0.0f;
    for (int m = 0; m < NMEL; m++) {
        float w = w1[j * NMEL + m];
#pragma unroll
        for (int b = 0; b < NB; b++) acc[b] += xl[b][m] * w;
    }
    for (int b = 0; b < NB; b++) pre[((size_t)t * NB + b) * NPRE + j] = fmaxf(acc[b], 0.0f);
}

__global__ __launch_bounds__(256) void prenet2_kernel(const float* __restrict__ w2,
                                                      float* __restrict__ pre) {
    int t = blockIdx.x;
    __shared__ float hl[NB][NPRE];
    for (int i = threadIdx.x; i < NB * NPRE; i += 256)
        hl[i / NPRE][i % NPRE] = pre[(size_t)t * NB * NPRE + i];
    __syncthreads();
    int j = threadIdx.x;
    float acc[NB];
#pragma unroll
    for (int b = 0; b < NB; b++) acc[b] = 0.0f;
    for (int k = 0; k < NPRE; k++) {
        float w = w2[j * NPRE + k];
#pragma unroll
        for (int b = 0; b < NB; b++) acc[b] += hl[b][k] * w;
    }
    for (int b = 0; b < NB; b++) pre[((size_t)t * NB + b) * NPRE + j] = fmaxf(acc[b], 0.0f);
}

// processed_memory TRANSPOSED: pmt[b][a][t]
__global__ __launch_bounds__(128) void pmt_kernel(const float* __restrict__ mem,
                                                  const float* __restrict__ mw,
                                                  float* __restrict__ pmt) {
    int b = blockIdx.y, t0 = blockIdx.x * 4;
    __shared__ float ml[4][NENC];
    for (int i = threadIdx.x; i < 4 * NENC; i += 128)
        ml[i / NENC][i % NENC] = mem[((size_t)b * TIN + t0 + i / NENC) * NENC + (i % NENC)];
    __syncthreads();
    int a = threadIdx.x;
    float acc[4] = {0, 0, 0, 0};
    for (int e = 0; e < NENC; e++) {
        float w = mw[a * NENC + e];
#pragma unroll
        for (int tt = 0; tt < 4; tt++) acc[tt] += ml[tt][e] * w;
    }
    *(float4*)&pmt[((size_t)b * NATT + a) * TIN + t0] = make_float4(acc[0], acc[1], acc[2], acc[3]);
}

// ---------------- persistent kernel ----------------
struct Params {
    const float* memory; const int* mlen;
    const float* awih; const float* awhh; const float* abih; const float* abhh;
    const float* qw; const float* vw; const float* wc; const float* ldw;
    const float* dwih; const float* dwhh; const float* dbih; const float* dbhh;
    const float* pjw; const float* pjb; const float* gtw; const float* gtb;
    float* ws; float* out;
};

// Monotone two-level grid barrier with RELAXED polls.
// Key: agent-scope RELAXED atomics read/modify at the coherence point but emit
// NO cache-maintenance ops. Exactly one release fence (before arrival) and one
// acquire fence (after release observed) per block per barrier — so spinning
// does not invalidate L2 (round-5 bug: acquire-polls = L2-invalidate storm).
__device__ __forceinline__ void gbar(unsigned* bar, unsigned n) {
    __syncthreads();
    if (threadIdx.x == 0) {
        __threadfence();   // release: make this block's writes visible (L2 wb)
        unsigned* grp  = bar + ((blockIdx.x >> 5) << 5);  // 8 groups, 128B apart
        unsigned* root = bar + 256;
        unsigned old = __hip_atomic_fetch_add(grp, 1u, __ATOMIC_RELAXED, __HIP_MEMORY_SCOPE_AGENT);
        if (old + 1u == (n << 5))
            __hip_atomic_fetch_add(root, 1u, __ATOMIC_RELAXED, __HIP_MEMORY_SCOPE_AGENT);
        while (__hip_atomic_load(root, __ATOMIC_RELAXED, __HIP_MEMORY_SCOPE_AGENT) < (n << 3))
            __builtin_amdgcn_s_sleep(2);
        __threadfence();   // acquire: invalidate stale L1/L2 before reading others' data
    }
    __syncthreads();
}

// ---- z GEMV: wave handles 2 cols; lane = (col: lane>>5, kpos: lane&31) ----
__device__ __forceinline__ void zreg128(const float* __restrict__ w,
                                        const float* __restrict__ x, int xs,
                                        int nticks, int kpos, float* acc) {
    for (int tk = 0; tk < nticks; ++tk) {
        int k = tk * 128 + kpos * 4;
        float4 w4 = *(const float4*)(w + k);
#pragma unroll
        for (int b = 0; b < NB; ++b) {
            float4 x4 = *(const float4*)(x + (size_t)b * xs + k);
            acc[b] = fmaf(w4.x, x4.x, acc[b]);
            acc[b] = fmaf(w4.y, x4.y, acc[b]);
            acc[b] = fmaf(w4.z, x4.z, acc[b]);
            acc[b] = fmaf(w4.w, x4.w, acc[b]);
        }
    }
}

// 4 cols/wave variant for K=512 (lane = col: lane>>4, kpos: lane&15)
__device__ __forceinline__ void zreg64(const float* __restrict__ w,
                                       const float* __restrict__ x, int xs,
                                       int nticks, int kpos, float* acc) {
    for (int tk = 0; tk < nticks; ++tk) {
        int k = tk * 64 + kpos * 4;
        float4 w4 = *(const float4*)(w + k);
#pragma unroll
        for (int b = 0; b < NB; ++b) {
            float4 x4 = *(const float4*)(x + (size_t)b * xs + k);
            acc[b] = fmaf(w4.x, x4.x, acc[b]);
            acc[b] = fmaf(w4.y, x4.y, acc[b]);
            acc[b] = fmaf(w4.z, x4.z, acc[b]);
            acc[b] = fmaf(w4.w, x4.w, acc[b]);
        }
    }
}

// main z item (16 cols): w<256 -> zd(t): dwih[:,:1024]@AH + dwhh@DH
//                        w>=256 -> za(ts): awih[:,:256]@PRE(ts) + awhh@AH
__device__ void z_main_item(const Params& p, int w, int ts, int tid) {
    int wv = tid >> 6, lane = tid & 63, colh = lane >> 5, kpos = lane & 31;
    float* ws = p.ws;
    float acc[NB];
#pragma unroll
    for (int b = 0; b < NB; ++b) acc[b] = 0.f;
    int gcol;
    float* zout;
    if (w < 256) {
        gcol = w * 16 + wv * 2 + colh;
        zreg128(p.dwih + (size_t)gcol * 1536, ws + WS_AH, NU, 8, kpos, acc);
        zreg128(p.dwhh + (size_t)gcol * NU, ws + WS_DH, NU, 8, kpos, acc);
        zout = ws + WS_ZD;
    } else {
        gcol = (w - 256) * 16 + wv * 2 + colh;
        zreg128(p.awih + (size_t)gcol * 768, ws + WS_PRE + (size_t)ts * NB * NPRE, NPRE, 2, kpos, acc);
        zreg128(p.awhh + (size_t)gcol * NU, ws + WS_AH, NU, 8, kpos, acc);
        zout = ws + WS_ZA;
    }
#pragma unroll
    for (int sh = 1; sh <= 16; sh <<= 1) {
#pragma unroll
        for (int b = 0; b < NB; ++b) acc[b] += __shfl_xor(acc[b], sh);
    }
    if (kpos == 0) {
#pragma unroll
        for (int b = 0; b < NB; ++b) zout[((size_t)b << 12) + gcol] = acc[b];
    }
}

// actx z item (32 cols): w<128 -> zd += dwih[:,1024:1536]@ACTX
//                        w>=128 -> za += awih[:,256:768]@ACTX
__device__ void z_actx_item(const Params& p, int w, int tid) {
    int wv = tid >> 6, lane = tid & 63, col4 = lane >> 4, kpos = lane & 15;
    float* ws = p.ws;
    float acc[NB];
#pragma unroll
    for (int b = 0; b < NB; ++b) acc[b] = 0.f;
    int gcol; const float* W; float* zout;
    if (w < 128) {
        gcol = w * 32 + wv * 4 + col4;
        W = p.dwih + (size_t)gcol * 1536 + 1024;
        zout = ws + WS_ZD;
    } else {
        gcol = (w - 128) * 32 + wv * 4 + col4;
        W = p.awih + (size_t)gcol * 768 + 256;
        zout = ws + WS_ZA;
    }
    zreg64(W, ws + WS_ACTX, NENC, 8, kpos, acc);
#pragma unroll
    for (int sh = 1; sh <= 8; sh <<= 1) {
#pragma unroll
        for (int b = 0; b < NB; ++b) acc[b] += __shfl_xor(acc[b], sh);
    }
    if (kpos == 0) {
#pragma unroll
        for (int b = 0; b < NB; ++b) zout[((size_t)b << 12) + gcol] += acc[b];
    }
}

// attn + ctx fused, one block per b:
// conv31 -> dense -> tanh -> vdot -> mask -> softmax -> aw -> ctx
__device__ void attn_ctx_block(const Params& p, int b, int step, int tid, float* sm) {
    float* ws = p.ws;
    float* awl = sm, *cuml = sm + 512, *pql = sm + 1024, *red = sm + 1152;
    awl[tid] = ws[WS_AW + b * 512 + tid];
    cuml[tid] = ws[WS_AWCUM + b * 512 + tid];
    if (tid < NATT) pql[tid] = ws[WS_PQ + b * NATT + tid];
    __syncthreads();
    int t = tid;
    float loc[32];
#pragma unroll
    for (int f = 0; f < 32; ++f) loc[f] = 0.f;
    for (int d = 0; d < 31; ++d) {
        int tp = t + d - 15;
        int tc = min(max(tp, 0), 511);
        bool ok = (tp >= 0) && (tp < 512);
        float a_ = ok ? awl[tc] : 0.f;
        float c_ = ok ? cuml[tc] : 0.f;
#pragma unroll
        for (int f = 0; f < 32; ++f)
            loc[f] = fmaf(a_, p.wc[f * 62 + d], fmaf(c_, p.wc[f * 62 + 31 + d], loc[f]));
    }
    float e = 0.f;
    const float* pmt = ws + WS_PM + (size_t)b * NATT * TIN + t;
    for (int a = 0; a < NATT; ++a) {
        float s = pql[a] + pmt[(size_t)a * TIN];
#pragma unroll
        for (int f = 0; f < 32; ++f) s = fmaf(loc[f], p.ldw[a * 32 + f], s);
        e = fmaf(ftanh(s), p.vw[a], e);
    }
    if (t >= p.mlen[b]) e = -3.0e38f;
    float m = e;
#pragma unroll
    for (int sh = 1; sh <= 32; sh <<= 1) m = fmaxf(m, __shfl_xor(m, sh));
    if ((tid & 63) == 0) red[tid >> 6] = m;
    __syncthreads();
    m = fmaxf(fmaxf(fmaxf(red[0], red[1]), fmaxf(red[2], red[3])),
              fmaxf(fmaxf(red[4], red[5]), fmaxf(red[6], red[7])));
    float pv = __expf(e - m);
    float ss = pv;
#pragma unroll
    for (int sh = 1; sh <= 32; sh <<= 1) ss += __shfl_xor(ss, sh);
    if ((tid & 63) == 0) red[8 + (tid >> 6)] = ss;
    __syncthreads();
    float tot = red[8] + red[9] + red[10] + red[11] + red[12] + red[13] + red[14] + red[15];
    float aw = pv / tot;
    ws[WS_AW + b * 512 + t] = aw;
    ws[WS_AWCUM + b * 512 + t] += aw;
    p.out[OUT_ALIGN + ((size_t)b * TOUT + step) * TIN + t] = aw;
    __syncthreads();
    awl[tid] = aw;       // awl now holds aw(t)
    __syncthreads();
    // ctx: thread = enc dim e
    const float* mb = p.memory + (size_t)b * TIN * NENC + tid;
    float acc = 0.f;
#pragma unroll 4
    for (int tt = 0; tt < TIN; ++tt)
        acc = fmaf(awl[tt], mb[(size_t)tt * NENC], acc);
    ws[WS_ACTX + b * NENC + tid] = acc;
}

__device__ void agates_pq(const Params& p, int b, int tid, float* sm) {
    float* ahl = sm;
    float* ws = p.ws;
    float* AH = ws + WS_AH + (size_t)b * NU;
    float* AC = ws + WS_AC + (size_t)b * NU;
    const float* Z = ws + WS_ZA + (size_t)b * NG;
    for (int u = tid; u < NU; u += NTHR) {
        float zi = Z[u]          + p.abih[u]          + p.abhh[u];
        float zf = Z[NU + u]     + p.abih[NU + u]     + p.abhh[NU + u];
        float zg = Z[2 * NU + u] + p.abih[2 * NU + u] + p.abhh[2 * NU + u];
        float zo = Z[3 * NU + u] + p.abih[3 * NU + u] + p.abhh[3 * NU + u];
        float c = fsigm(zf) * AC[u] + fsigm(zi) * ftanh(zg);
        float h = fsigm(zo) * ftanh(c);
        AC[u] = c; AH[u] = h; ahl[u] = h;
    }
    __syncthreads();
    int a = tid >> 2, q = tid & 3;
    const float* qr = p.qw + (size_t)a * NU + q * 256;
    const float* h4 = ahl + q * 256;
    float s = 0.f;
#pragma unroll
    for (int k4 = 0; k4 < 64; k4++) {
        float4 hv = *(const float4*)(h4 + k4 * 4);
        float4 wv = *(const float4*)(qr + k4 * 4);
        s = fmaf(hv.x, wv.x, s); s = fmaf(hv.y, wv.y, s);
        s = fmaf(hv.z, wv.z, s); s = fmaf(hv.w, wv.w, s);
    }
    s += __shfl_xor(s, 1); s += __shfl_xor(s, 2);
    if (q == 0) ws[WS_PQ + b * NATT + a] = s;
    __syncthreads();
}

__device__ void dgates_proj(const Params& p, int b, int t, int tid, float* sm) {
    float* dhc = sm;
    float* ws = p.ws;
    float* DH = ws + WS_DH + (size_t)b * NU;
    float* DC = ws + WS_DC + (size_t)b * NU;
    const float* Z = ws + WS_ZD + (size_t)b * NG;
    for (int u = tid; u < NU; u += NTHR) {
        float zi = Z[u]          + p.dbih[u]          + p.dbhh[u];
        float zf = Z[NU + u]     + p.dbih[NU + u]     + p.dbhh[NU + u];
        float zg = Z[2 * NU + u] + p.dbih[2 * NU + u] + p.dbhh[2 * NU + u];
        float zo = Z[3 * NU + u] + p.dbih[3 * NU + u] + p.dbhh[3 * NU + u];
        float c = fsigm(zf) * DC[u] + fsigm(zi) * ftanh(zg);
        float h = fsigm(zo) * ftanh(c);
        DC[u] = c; DH[u] = h; dhc[u] = h;
    }
    for (int i = tid; i < NENC; i += NTHR) dhc[NU + i] = ws[WS_ACTX + b * NENC + i];
    __syncthreads();
    int col = tid >> 2, q = tid & 3;
    if (col < 81) {
        const float* wr = (col < 80) ? (p.pjw + (size_t)col * 1536) : p.gtw;
        const float* d4 = dhc + q * 384;
        const float* w4 = wr + q * 384;
        float s = 0.f;
#pragma unroll
        for (int k4 = 0; k4 < 96; k4++) {
            float4 hv = *(const float4*)(d4 + k4 * 4);
            float4 wv = *(const float4*)(w4 + k4 * 4);
            s = fmaf(hv.x, wv.x, s); s = fmaf(hv.y, wv.y, s);
            s = fmaf(hv.z, wv.z, s); s = fmaf(hv.w, wv.w, s);
        }
        s += __shfl_xor(s, 1); s += __shfl_xor(s, 2);
        if (q == 0) {
            s += (col < 80) ? p.pjb[col] : p.gtb[0];
            if (col < 80) p.out[((size_t)b * NMEL + col) * TOUT + t] = s;
            else          p.out[(size_t)NB * NMEL * TOUT + (size_t)b * TOUT + t] = s;
        }
    }
    __syncthreads();
}

__global__ __launch_bounds__(NTHR, 2) void persist_kernel(Params p) {
    __shared__ float sm[1664];
    int tid = threadIdx.x, bid = blockIdx.x;
    unsigned* bar = (unsigned*)(p.ws + WS_BAR);
    unsigned nb_ = 0;

    // prologue: za(0) main part (actx(-1)=0 -> no actx part), then agates+pq(0)
    z_main_item(p, 256 + bid, 0, tid);
    ++nb_; gbar(bar, nb_);
    if (bid >= 32 && bid < 64) agates_pq(p, bid - 32, tid, sm);
    ++nb_; gbar(bar, nb_);

    for (int t = 0; t < TOUT; ++t) {
        // P1: attn+ctx(t) [32 blocks] || z-main: zd(t) + za(t+1) [224 blocks]
        if (bid < 32) attn_ctx_block(p, bid, t, tid, sm);
        else {
            for (int w = bid - 32; w < 512; w += (NBLK - 32)) {
                if (w < 256) z_main_item(p, w, 0, tid);
                else if (t + 1 < TOUT) z_main_item(p, w, t + 1, tid);
            }
        }
        ++nb_; gbar(bar, nb_);
        // P2: z-actx: zd(t) += Wd_actx@actx(t); za(t+1) += Wa_actx@actx(t)
        if (bid < 128 || t + 1 < TOUT) z_actx_item(p, bid, tid);
        ++nb_; gbar(bar, nb_);
        // P3: dgates+proj(t) [32] || agates+pq(t+1) [32]
        if (bid < 32) dgates_proj(p, bid, t, tid, sm);
        else if (bid < 64 && t + 1 < TOUT) agates_pq(p, bid - 32, tid, sm);
        ++nb_; gbar(bar, nb_);
    }

    // self-reset barrier counters (safe: done==NBLK proves nobody still spins)
    if (tid == 0) {
        unsigned* done = bar + 288;
        unsigned old = __hip_atomic_fetch_add(done, 1u, __ATOMIC_RELAXED, __HIP_MEMORY_SCOPE_AGENT);
        if (old == NBLK - 1u) {
#pragma unroll
            for (int i = 0; i < 8; ++i)
                __hip_atomic_store(bar + i * 32, 0u, __ATOMIC_RELAXED, __HIP_MEMORY_SCOPE_AGENT);
            __hip_atomic_store(bar + 256, 0u, __ATOMIC_RELAXED, __HIP_MEMORY_SCOPE_AGENT);
            __hip_atomic_store(bar + 288, 0u, __ATOMIC_RELAXED, __HIP_MEMORY_SCOPE_AGENT);
        }
    }
}

extern "C" void kernel_launch(void* const* d_in, const int* in_sizes, int n_in,
                              void* d_out, int out_size, void* d_ws, size_t ws_size,
                              hipStream_t stream) {
    const float* memory = (const float*)d_in[0];
    const float* dec    = (const float*)d_in[1];
    const int*   mlen   = (const int*)d_in[2];
    const float* pw1    = (const float*)d_in[3];
    const float* pw2    = (const float*)d_in[4];
    const float* awih   = (const float*)d_in[5];
    const float* awhh   = (const float*)d_in[6];
    const float* abih   = (const float*)d_in[7];
    const float* abhh   = (const float*)d_in[8];
    const float* qw     = (const float*)d_in[9];
    const float* mw     = (const float*)d_in[10];
    const float* vw     = (const float*)d_in[11];
    const float* wc     = (const float*)d_in[12];
    const float* ldw    = (const float*)d_in[13];
    const float* dwih   = (const float*)d_in[14];
    const float* dwhh   = (const float*)d_in[15];
    const float* dbih   = (const float*)d_in[16];
    const float* dbhh   = (const float*)d_in[17];
    const float* pjw    = (const float*)d_in[18];
    const float* pjb    = (const float*)d_in[19];
    const float* gtw    = (const float*)d_in[20];
    const float* gtb    = (const float*)d_in[21];
    float* ws  = (float*)d_ws;
    float* out = (float*)d_out;

    hipMemsetAsync(d_ws, 0, WS_ZERO_BYTES, stream);
    prenet1_kernel<<<TOUT, 256, 0, stream>>>(dec, pw1, ws + WS_PRE);
    prenet2_kernel<<<TOUT, 256, 0, stream>>>(pw2, ws + WS_PRE);
    pmt_kernel<<<dim3(TIN / 4, NB), 128, 0, stream>>>(memory, mw, ws + WS_PM);

    Params pp = { memory, mlen, awih, awhh, abih, abhh, qw, vw, wc, ldw,
                  dwih, dwhh, dbih, dbhh, pjw, pjb, gtw, gtb, ws, out };
    void* args[] = { &pp };
    hipLaunchCooperativeKernel((const void*)persist_kernel, dim3(NBLK), dim3(NTHR),
                               args, 0, stream);
}

// Round 7
// 186130.164 us; speedup vs baseline: 2.0622x; 1.0363x over previous
//
#include <hip/hip_runtime.h>
#include <math.h>

#define NB 32
#define TIN 512
#define TOUT 512
#define NENC 512
#define NATT 128
#define NU 1024
#define NG 4096
#define NPRE 256
#define NMEL 80
#define NBLK 256
#define NTHR 512

// ws offsets (floats)
#define WS_AH    0u
#define WS_AC    32768u
#define WS_DH    65536u
#define WS_DC    98304u
#define WS_ACTX  131072u
#define WS_AW    147456u
#define WS_AWCUM 163840u
#define WS_PQ    196608u
#define WS_BAR   200704u                    // 512 uints
#define WS_ZA    201216u                    // 32*4096
#define WS_ZD    332288u                    // 32*4096
#define WS_PM    463360u                    // 32*128*512 (transposed [b][a][t])
#define WS_PRE   2560512u                   // 512*32*256
#define WS_ZERO_BYTES (WS_ZA * 4u)
#define OUT_ALIGN ((size_t)NB * NMEL * TOUT + (size_t)NB * TOUT)

__device__ __forceinline__ float fsigm(float x) { return 1.f / (1.f + __expf(-x)); }
__device__ __forceinline__ float ftanh(float x) { return 1.f - 2.f / (__expf(2.f * x) + 1.f); }

// write-through store to the coherence point (bypasses L1/L2 dirty state)
__device__ __forceinline__ void st_wt(float* p, float v) {
    asm volatile("global_store_dword %0, %1, off sc0 sc1" :: "v"(p), "v"(v) : "memory");
}

// ---------------- setup kernels ----------------
__global__ __launch_bounds__(256) void prenet1_kernel(const float* __restrict__ dec,
                                                      const float* __restrict__ w1,
                                                      float* __restrict__ pre) {
    int t = blockIdx.x;
    __shared__ float xl[NB][NMEL];
    for (int i = threadIdx.x; i < NB * NMEL; i += 256) {
        int b = i / NMEL, m = i % NMEL;
        xl[b][m] = (t == 0) ? 0.0f : dec[(b * NMEL + m) * TOUT + (t - 1)];
    }
    __syncthreads();
    int j = threadIdx.x;
    float acc[NB];
#pragma unroll
    for (int b = 0; b < NB; b++) acc[b] = 0.0f;
    for (int m = 0; m < NMEL; m++) {
        float w = w1[j * NMEL + m];
#pragma unroll
        for (int b = 0; b < NB; b++) acc[b] += xl[b][m] * w;
    }
    for (int b = 0; b < NB; b++) pre[((size_t)t * NB + b) * NPRE + j] = fmaxf(acc[b], 0.0f);
}

__global__ __launch_bounds__(256) void prenet2_kernel(const float* __restrict__ w2,
                                                      float* __restrict__ pre) {
    int t = blockIdx.x;
    __shared__ float hl[NB][NPRE];
    for (int i = threadIdx.x; i < NB * NPRE; i += 256)
        hl[i / NPRE][i % NPRE] = pre[(size_t)t * NB * NPRE + i];
    __syncthreads();
    int j = threadIdx.x;
    float acc[NB];
#pragma unroll
    for (int b = 0; b < NB; b++) acc[b] = 0.0f;
    for (int k = 0; k < NPRE; k++) {
        float w = w2[j * NPRE + k];
#pragma unroll
        for (int b = 0; b < NB; b++) acc[b] += hl[b][k] * w;
    }
    for (int b = 0; b < NB; b++) pre[((size_t)t * NB + b) * NPRE + j] = fmaxf(acc[b], 0.0f);
}

// processed_memory TRANSPOSED: pmt[b][a][t]
__global__ __launch_bounds__(128) void pmt_kernel(const float* __restrict__ mem,
                                                  const float* __restrict__ mw,
                                                  float* __restrict__ pmt) {
    int b = blockIdx.y, t0 = blockIdx.x * 4;
    __shared__ float ml[4][NENC];
    for (int i = threadIdx.x; i < 4 * NENC; i += 128)
        ml[i / NENC][i % NENC] = mem[((size_t)b * TIN + t0 + i / NENC) * NENC + (i % NENC)];
    __syncthreads();
    int a = threadIdx.x;
    float acc[4] = {0, 0, 0, 0};
    for (int e = 0; e < NENC; e++) {
        float w = mw[a * NENC + e];
#pragma unroll
        for (int tt = 0; tt < 4; tt++) acc[tt] += ml[tt][e] * w;
    }
    *(float4*)&pmt[((size_t)b * NATT + a) * TIN + t0] = make_float4(acc[0], acc[1], acc[2], acc[3]);
}

// ---------------- persistent kernel ----------------
struct Params {
    const float* memory; const int* mlen;
    const float* awih; const float* awhh; const float* abih; const float* abhh;
    const float* qw; const float* vw; const float* wc; const float* ldw;
    const float* dwih; const float* dwhh; const float* dbih; const float* dbhh;
    const float* pjw; const float* pjb; const float* gtw; const float* gtb;
    float* ws; float* out;
};

// Two-stage monotone grid barrier. Stage 1: all blocks arrive (relaxed RMWs at
// the coherence point, no cache ops). Stage 2: exactly ONE designated block per
// XCD does {wbl2, full inv}; everyone else waits on root2 then does an L1-only
// inv. Cross-block stores are write-through (st_wt), so no per-block release
// writeback is needed — __syncthreads' vmcnt(0) drain makes them visible.
// bar layout (uints): [0..255] grp lines, [256] root, [288] done, [320] root2,
//                     [352..415] claim, [416] ninv
__device__ __forceinline__ void gbar(unsigned* bar, unsigned n, bool am_inv) {
    asm volatile("s_waitcnt vmcnt(0)" ::: "memory");
    __syncthreads();
    if (threadIdx.x == 0) {
        unsigned* grp   = bar + ((blockIdx.x >> 5) << 5);
        unsigned* root  = bar + 256;
        unsigned* root2 = bar + 320;
        unsigned old = __hip_atomic_fetch_add(grp, 1u, __ATOMIC_RELAXED, __HIP_MEMORY_SCOPE_AGENT);
        if (old + 1u == (n << 5))
            __hip_atomic_fetch_add(root, 1u, __ATOMIC_RELAXED, __HIP_MEMORY_SCOPE_AGENT);
        while (__hip_atomic_load(root, __ATOMIC_RELAXED, __HIP_MEMORY_SCOPE_AGENT) < (n << 3))
            __builtin_amdgcn_s_sleep(1);
        unsigned ninv = __hip_atomic_load(bar + 416, __ATOMIC_RELAXED, __HIP_MEMORY_SCOPE_AGENT);
        if (am_inv) {
            asm volatile("buffer_wbl2 sc1\n\t"
                         "s_waitcnt vmcnt(0)\n\t"
                         "buffer_inv sc0 sc1\n\t"
                         "s_waitcnt vmcnt(0)" ::: "memory");
            __hip_atomic_fetch_add(root2, 1u, __ATOMIC_RELAXED, __HIP_MEMORY_SCOPE_AGENT);
        }
        while (__hip_atomic_load(root2, __ATOMIC_RELAXED, __HIP_MEMORY_SCOPE_AGENT) < n * ninv)
            __builtin_amdgcn_s_sleep(1);
        asm volatile("buffer_inv sc0" ::: "memory");   // L1-only
    }
    __syncthreads();
}

// ---- z GEMV: wave handles 2 cols; lane = (col: lane>>5, kpos: lane&31) ----
__device__ __forceinline__ void zreg128(const float* __restrict__ w,
                                        const float* __restrict__ x, int xs,
                                        int nticks, int kpos, float* acc) {
    for (int tk = 0; tk < nticks; ++tk) {
        int k = tk * 128 + kpos * 4;
        float4 w4 = *(const float4*)(w + k);
#pragma unroll
        for (int b = 0; b < NB; ++b) {
            float4 x4 = *(const float4*)(x + (size_t)b * xs + k);
            acc[b] = fmaf(w4.x, x4.x, acc[b]);
            acc[b] = fmaf(w4.y, x4.y, acc[b]);
            acc[b] = fmaf(w4.z, x4.z, acc[b]);
            acc[b] = fmaf(w4.w, x4.w, acc[b]);
        }
    }
}

// 4 cols/wave variant for K=512 (lane = col: lane>>4, kpos: lane&15)
__device__ __forceinline__ void zreg64(const float* __restrict__ w,
                                       const float* __restrict__ x, int xs,
                                       int nticks, int kpos, float* acc) {
    for (int tk = 0; tk < nticks; ++tk) {
        int k = tk * 64 + kpos * 4;
        float4 w4 = *(const float4*)(w + k);
#pragma unroll
        for (int b = 0; b < NB; ++b) {
            float4 x4 = *(const float4*)(x + (size_t)b * xs + k);
            acc[b] = fmaf(w4.x, x4.x, acc[b]);
            acc[b] = fmaf(w4.y, x4.y, acc[b]);
            acc[b] = fmaf(w4.z, x4.z, acc[b]);
            acc[b] = fmaf(w4.w, x4.w, acc[b]);
        }
    }
}

// main z item (16 cols): w<256 -> zd(t): dwih[:,:1024]@AH + dwhh@DH
//                        w>=256 -> za(ts): awih[:,:256]@PRE(ts) + awhh@AH
__device__ void z_main_item(const Params& p, int w, int ts, int tid) {
    int wv = tid >> 6, lane = tid & 63, colh = lane >> 5, kpos = lane & 31;
    float* ws = p.ws;
    float acc[NB];
#pragma unroll
    for (int b = 0; b < NB; ++b) acc[b] = 0.f;
    int gcol;
    float* zout;
    if (w < 256) {
        gcol = w * 16 + wv * 2 + colh;
        zreg128(p.dwih + (size_t)gcol * 1536, ws + WS_AH, NU, 8, kpos, acc);
        zreg128(p.dwhh + (size_t)gcol * NU, ws + WS_DH, NU, 8, kpos, acc);
        zout = ws + WS_ZD;
    } else {
        gcol = (w - 256) * 16 + wv * 2 + colh;
        zreg128(p.awih + (size_t)gcol * 768, ws + WS_PRE + (size_t)ts * NB * NPRE, NPRE, 2, kpos, acc);
        zreg128(p.awhh + (size_t)gcol * NU, ws + WS_AH, NU, 8, kpos, acc);
        zout = ws + WS_ZA;
    }
#pragma unroll
    for (int sh = 1; sh <= 16; sh <<= 1) {
#pragma unroll
        for (int b = 0; b < NB; ++b) acc[b] += __shfl_xor(acc[b], sh);
    }
    if (kpos == 0) {
#pragma unroll
        for (int b = 0; b < NB; ++b) st_wt(&zout[((size_t)b << 12) + gcol], acc[b]);
    }
}

// actx z item (32 cols): w<128 -> zd += dwih[:,1024:1536]@ACTX
//                        w>=128 -> za += awih[:,256:768]@ACTX
__device__ void z_actx_item(const Params& p, int w, int tid) {
    int wv = tid >> 6, lane = tid & 63, col4 = lane >> 4, kpos = lane & 15;
    float* ws = p.ws;
    float acc[NB];
#pragma unroll
    for (int b = 0; b < NB; ++b) acc[b] = 0.f;
    int gcol; const float* W; float* zout;
    if (w < 128) {
        gcol = w * 32 + wv * 4 + col4;
        W = p.dwih + (size_t)gcol * 1536 + 1024;
        zout = ws + WS_ZD;
    } else {
        gcol = (w - 128) * 32 + wv * 4 + col4;
        W = p.awih + (size_t)gcol * 768 + 256;
        zout = ws + WS_ZA;
    }
    zreg64(W, ws + WS_ACTX, NENC, 8, kpos, acc);
#pragma unroll
    for (int sh = 1; sh <= 8; sh <<= 1) {
#pragma unroll
        for (int b = 0; b < NB; ++b) acc[b] += __shfl_xor(acc[b], sh);
    }
    if (kpos == 0) {
#pragma unroll
        for (int b = 0; b < NB; ++b) {
            float* zp = &zout[((size_t)b << 12) + gcol];
            st_wt(zp, *zp + acc[b]);
        }
    }
}

// attn + ctx fused, one block per b:
// conv31 -> dense -> tanh -> vdot -> mask -> softmax -> aw -> ctx
__device__ void attn_ctx_block(const Params& p, int b, int step, int tid, float* sm) {
    float* ws = p.ws;
    float* awl = sm, *cuml = sm + 512, *pql = sm + 1024, *red = sm + 1152;
    awl[tid] = ws[WS_AW + b * 512 + tid];
    cuml[tid] = ws[WS_AWCUM + b * 512 + tid];
    if (tid < NATT) pql[tid] = ws[WS_PQ + b * NATT + tid];
    __syncthreads();
    int t = tid;
    float loc[32];
#pragma unroll
    for (int f = 0; f < 32; ++f) loc[f] = 0.f;
    for (int d = 0; d < 31; ++d) {
        int tp = t + d - 15;
        int tc = min(max(tp, 0), 511);
        bool ok = (tp >= 0) && (tp < 512);
        float a_ = ok ? awl[tc] : 0.f;
        float c_ = ok ? cuml[tc] : 0.f;
#pragma unroll
        for (int f = 0; f < 32; ++f)
            loc[f] = fmaf(a_, p.wc[f * 62 + d], fmaf(c_, p.wc[f * 62 + 31 + d], loc[f]));
    }
    float e = 0.f;
    const float* pmt = ws + WS_PM + (size_t)b * NATT * TIN + t;
    for (int a = 0; a < NATT; ++a) {
        float s = pql[a] + pmt[(size_t)a * TIN];
#pragma unroll
        for (int f = 0; f < 32; ++f) s = fmaf(loc[f], p.ldw[a * 32 + f], s);
        e = fmaf(ftanh(s), p.vw[a], e);
    }
    if (t >= p.mlen[b]) e = -3.0e38f;
    float m = e;
#pragma unroll
    for (int sh = 1; sh <= 32; sh <<= 1) m = fmaxf(m, __shfl_xor(m, sh));
    if ((tid & 63) == 0) red[tid >> 6] = m;
    __syncthreads();
    m = fmaxf(fmaxf(fmaxf(red[0], red[1]), fmaxf(red[2], red[3])),
              fmaxf(fmaxf(red[4], red[5]), fmaxf(red[6], red[7])));
    float pv = __expf(e - m);
    float ss = pv;
#pragma unroll
    for (int sh = 1; sh <= 32; sh <<= 1) ss += __shfl_xor(ss, sh);
    if ((tid & 63) == 0) red[8 + (tid >> 6)] = ss;
    __syncthreads();
    float tot = red[8] + red[9] + red[10] + red[11] + red[12] + red[13] + red[14] + red[15];
    float aw = pv / tot;
    ws[WS_AW + b * 512 + t] = aw;                     // private to this block
    ws[WS_AWCUM + b * 512 + t] += aw;                 // private to this block
    p.out[OUT_ALIGN + ((size_t)b * TOUT + step) * TIN + t] = aw;
    __syncthreads();
    awl[tid] = aw;       // awl now holds aw(t)
    __syncthreads();
    // ctx: thread = enc dim e
    const float* mb = p.memory + (size_t)b * TIN * NENC + tid;
    float acc = 0.f;
#pragma unroll 4
    for (int tt = 0; tt < TIN; ++tt)
        acc = fmaf(awl[tt], mb[(size_t)tt * NENC], acc);
    st_wt(&ws[WS_ACTX + b * NENC + tid], acc);        // cross-block
}

__device__ void agates_pq(const Params& p, int b, int tid, float* sm) {
    float* ahl = sm;
    float* ws = p.ws;
    float* AH = ws + WS_AH + (size_t)b * NU;
    float* AC = ws + WS_AC + (size_t)b * NU;
    const float* Z = ws + WS_ZA + (size_t)b * NG;
    for (int u = tid; u < NU; u += NTHR) {
        float zi = Z[u]          + p.abih[u]          + p.abhh[u];
        float zf = Z[NU + u]     + p.abih[NU + u]     + p.abhh[NU + u];
        float zg = Z[2 * NU + u] + p.abih[2 * NU + u] + p.abhh[2 * NU + u];
        float zo = Z[3 * NU + u] + p.abih[3 * NU + u] + p.abhh[3 * NU + u];
        float c = fsigm(zf) * AC[u] + fsigm(zi) * ftanh(zg);
        float h = fsigm(zo) * ftanh(c);
        AC[u] = c;                 // private (same block every step)
        st_wt(&AH[u], h);          // cross-block
        ahl[u] = h;
    }
    __syncthreads();
    int a = tid >> 2, q = tid & 3;
    const float* qr = p.qw + (size_t)a * NU + q * 256;
    const float* h4 = ahl + q * 256;
    float s = 0.f;
#pragma unroll
    for (int k4 = 0; k4 < 64; k4++) {
        float4 hv = *(const float4*)(h4 + k4 * 4);
        float4 wv = *(const float4*)(qr + k4 * 4);
        s = fmaf(hv.x, wv.x, s); s = fmaf(hv.y, wv.y, s);
        s = fmaf(hv.z, wv.z, s); s = fmaf(hv.w, wv.w, s);
    }
    s += __shfl_xor(s, 1); s += __shfl_xor(s, 2);
    if (q == 0) st_wt(&ws[WS_PQ + b * NATT + a], s);  // cross-block
    __syncthreads();
}

__device__ void dgates_proj(const Params& p, int b, int t, int tid, float* sm) {
    float* dhc = sm;
    float* ws = p.ws;
    float* DH = ws + WS_DH + (size_t)b * NU;
    float* DC = ws + WS_DC + (size_t)b * NU;
    const float* Z = ws + WS_ZD + (size_t)b * NG;
    for (int u = tid; u < NU; u += NTHR) {
        float zi = Z[u]          + p.dbih[u]          + p.dbhh[u];
        float zf = Z[NU + u]     + p.dbih[NU + u]     + p.dbhh[NU + u];
        float zg = Z[2 * NU + u] + p.dbih[2 * NU + u] + p.dbhh[2 * NU + u];
        float zo = Z[3 * NU + u] + p.dbih[3 * NU + u] + p.dbhh[3 * NU + u];
        float c = fsigm(zf) * DC[u] + fsigm(zi) * ftanh(zg);
        float h = fsigm(zo) * ftanh(c);
        DC[u] = c;                 // private
        st_wt(&DH[u], h);          // cross-block
        dhc[u] = h;
    }
    for (int i = tid; i < NENC; i += NTHR) dhc[NU + i] = ws[WS_ACTX + b * NENC + i];
    __syncthreads();
    int col = tid >> 2, q = tid & 3;
    if (col < 81) {
        const float* wr = (col < 80) ? (p.pjw + (size_t)col * 1536) : p.gtw;
        const float* d4 = dhc + q * 384;
        const float* w4 = wr + q * 384;
        float s = 0.f;
#pragma unroll
        for (int k4 = 0; k4 < 96; k4++) {
            float4 hv = *(const float4*)(d4 + k4 * 4);
            float4 wv = *(const float4*)(w4 + k4 * 4);
            s = fmaf(hv.x, wv.x, s); s = fmaf(hv.y, wv.y, s);
            s = fmaf(hv.z, wv.z, s); s = fmaf(hv.w, wv.w, s);
        }
        s += __shfl_xor(s, 1); s += __shfl_xor(s, 2);
        if (q == 0) {
            s += (col < 80) ? p.pjb[col] : p.gtb[0];
            if (col < 80) p.out[((size_t)b * NMEL + col) * TOUT + t] = s;
            else          p.out[(size_t)NB * NMEL * TOUT + (size_t)b * TOUT + t] = s;
        }
    }
    __syncthreads();
}

__global__ __launch_bounds__(NTHR, 2) void persist_kernel(Params p) {
    __shared__ float sm[1664];
    int tid = threadIdx.x, bid = blockIdx.x;
    unsigned* bar = (unsigned*)(p.ws + WS_BAR);
    unsigned nb_ = 0;
    bool am_inv = false;

    // claim per-XCD invalidator role (once; counters zeroed by host memset)
    if (tid == 0) {
        unsigned xcd;
        asm volatile("s_getreg_b32 %0, hwreg(HW_REG_XCC_ID)" : "=s"(xcd));
        unsigned old = __hip_atomic_fetch_add(bar + 352 + (xcd & 63u), 1u,
                                              __ATOMIC_RELAXED, __HIP_MEMORY_SCOPE_AGENT);
        if (old == 0u) {
            __hip_atomic_fetch_add(bar + 416, 1u, __ATOMIC_RELAXED, __HIP_MEMORY_SCOPE_AGENT);
            am_inv = true;
        }
    }

    // prologue: za(0) main part (actx(-1)=0 -> no actx part), then agates+pq(0)
    z_main_item(p, 256 + bid, 0, tid);
    ++nb_; gbar(bar, nb_, am_inv);
    if (bid >= 32 && bid < 64) agates_pq(p, bid - 32, tid, sm);
    ++nb_; gbar(bar, nb_, am_inv);

    for (int t = 0; t < TOUT; ++t) {
        // P1: attn+ctx(t) [32 blocks] || z-main: zd(t) + za(t+1) [224 blocks]
        if (bid < 32) attn_ctx_block(p, bid, t, tid, sm);
        else {
            for (int w = bid - 32; w < 512; w += (NBLK - 32)) {
                if (w < 256) z_main_item(p, w, 0, tid);
                else if (t + 1 < TOUT) z_main_item(p, w, t + 1, tid);
            }
        }
        ++nb_; gbar(bar, nb_, am_inv);
        // P2: z-actx: zd(t) += Wd_actx@actx(t); za(t+1) += Wa_actx@actx(t)
        if (bid < 128 || t + 1 < TOUT) z_actx_item(p, bid, tid);
        ++nb_; gbar(bar, nb_, am_inv);
        // P3: dgates+proj(t) [32] || agates+pq(t+1) [32]
        if (bid < 32) dgates_proj(p, bid, t, tid, sm);
        else if (bid < 64 && t + 1 < TOUT) agates_pq(p, bid - 32, tid, sm);
        ++nb_; gbar(bar, nb_, am_inv);
    }

    // self-reset barrier region (safe: done==NBLK proves nobody still spins)
    if (tid == 0) {
        unsigned* done = bar + 288;
        unsigned old = __hip_atomic_fetch_add(done, 1u, __ATOMIC_RELAXED, __HIP_MEMORY_SCOPE_AGENT);
        if (old == NBLK - 1u) {
#pragma unroll
            for (int i = 0; i < 8; ++i)
                __hip_atomic_store(bar + i * 32, 0u, __ATOMIC_RELAXED, __HIP_MEMORY_SCOPE_AGENT);
            __hip_atomic_store(bar + 256, 0u, __ATOMIC_RELAXED, __HIP_MEMORY_SCOPE_AGENT);
            __hip_atomic_store(bar + 320, 0u, __ATOMIC_RELAXED, __HIP_MEMORY_SCOPE_AGENT);
            for (int i = 0; i < 64; ++i)
                __hip_atomic_store(bar + 352 + i, 0u, __ATOMIC_RELAXED, __HIP_MEMORY_SCOPE_AGENT);
            __hip_atomic_store(bar + 416, 0u, __ATOMIC_RELAXED, __HIP_MEMORY_SCOPE_AGENT);
            __hip_atomic_store(bar + 288, 0u, __ATOMIC_RELAXED, __HIP_MEMORY_SCOPE_AGENT);
        }
    }
}

extern "C" void kernel_launch(void* const* d_in, const int* in_sizes, int n_in,
                              void* d_out, int out_size, void* d_ws, size_t ws_size,
                              hipStream_t stream) {
    const float* memory = (const float*)d_in[0];
    const float* dec    = (const float*)d_in[1];
    const int*   mlen   = (const int*)d_in[2];
    const float* pw1    = (const float*)d_in[3];
    const float* pw2    = (const float*)d_in[4];
    const float* awih   = (const float*)d_in[5];
    const float* awhh   = (const float*)d_in[6];
    const float* abih   = (const float*)d_in[7];
    const float* abhh   = (const float*)d_in[8];
    const float* qw     = (const float*)d_in[9];
    const float* mw     = (const float*)d_in[10];
    const float* vw     = (const float*)d_in[11];
    const float* wc     = (const float*)d_in[12];
    const float* ldw    = (const float*)d_in[13];
    const float* dwih   = (const float*)d_in[14];
    const float* dwhh   = (const float*)d_in[15];
    const float* dbih   = (const float*)d_in[16];
    const float* dbhh   = (const float*)d_in[17];
    const float* pjw    = (const float*)d_in[18];
    const float* pjb    = (const float*)d_in[19];
    const float* gtw    = (const float*)d_in[20];
    const float* gtb    = (const float*)d_in[21];
    float* ws  = (float*)d_ws;
    float* out = (float*)d_out;

    hipMemsetAsync(d_ws, 0, WS_ZERO_BYTES, stream);
    prenet1_kernel<<<TOUT, 256, 0, stream>>>(dec, pw1, ws + WS_PRE);
    prenet2_kernel<<<TOUT, 256, 0, stream>>>(pw2, ws + WS_PRE);
    pmt_kernel<<<dim3(TIN / 4, NB), 128, 0, stream>>>(memory, mw, ws + WS_PM);

    Params pp = { memory, mlen, awih, awhh, abih, abhh, qw, vw, wc, ldw,
                  dwih, dwhh, dbih, dbhh, pjw, pjb, gtw, gtb, ws, out };
    void* args[] = { &pp };
    hipLaunchCooperativeKernel((const void*)persist_kernel, dim3(NBLK), dim3(NTHR),
                               args, 0, stream);
}

// Round 8
// 172250.305 us; speedup vs baseline: 2.2284x; 1.0806x over previous
//
#include <hip/hip_runtime.h>
#include <math.h>

#define NB 32
#define TIN 512
#define TOUT 512
#define NENC 512
#define NATT 128
#define NU 1024
#define NG 4096
#define NPRE 256
#define NMEL 80
#define NBLK 256
#define NTHR 512

// ws offsets (floats)
#define WS_AH    0u
#define WS_AC    32768u
#define WS_DH    65536u
#define WS_DC    98304u
#define WS_ACTX  131072u
#define WS_AW    147456u
#define WS_AWCUM 163840u
#define WS_PQ    180224u
#define WS_BAR   184320u                    // 512 uints
#define WS_ZD0   184832u                    // 32*4096 each
#define WS_ZD1   315904u
#define WS_ZDA   446976u
#define WS_ZA0   578048u
#define WS_ZAA   709120u
#define WS_PM    840192u                    // 32*128*512 ([b][a][t])
#define WS_PRE   2937344u                   // 512*32*256
#define WS_ZERO_BYTES (WS_PM * 4u)
#define OUT_ALIGN ((size_t)NB * NMEL * TOUT + (size_t)NB * TOUT)

__device__ __forceinline__ float fsigm(float x) { return 1.f / (1.f + __expf(-x)); }
__device__ __forceinline__ float ftanh(float x) { return 1.f - 2.f / (__expf(2.f * x) + 1.f); }

// write-through store to the coherence point
__device__ __forceinline__ void st_wt(float* p, float v) {
    asm volatile("global_store_dword %0, %1, off sc0 sc1" :: "v"(p), "v"(v) : "memory");
}

// ---------------- setup kernels ----------------
__global__ __launch_bounds__(256) void prenet1_kernel(const float* __restrict__ dec,
                                                      const float* __restrict__ w1,
                                                      float* __restrict__ pre) {
    int t = blockIdx.x;
    __shared__ float xl[NB][NMEL];
    for (int i = threadIdx.x; i < NB * NMEL; i += 256) {
        int b = i / NMEL, m = i % NMEL;
        xl[b][m] = (t == 0) ? 0.0f : dec[(b * NMEL + m) * TOUT + (t - 1)];
    }
    __syncthreads();
    int j = threadIdx.x;
    float acc[NB];
#pragma unroll
    for (int b = 0; b < NB; b++) acc[b] = 0.0f;
    for (int m = 0; m < NMEL; m++) {
        float w = w1[j * NMEL + m];
#pragma unroll
        for (int b = 0; b < NB; b++) acc[b] += xl[b][m] * w;
    }
    for (int b = 0; b < NB; b++) pre[((size_t)t * NB + b) * NPRE + j] = fmaxf(acc[b], 0.0f);
}

__global__ __launch_bounds__(256) void prenet2_kernel(const float* __restrict__ w2,
                                                      float* __restrict__ pre) {
    int t = blockIdx.x;
    __shared__ float hl[NB][NPRE];
    for (int i = threadIdx.x; i < NB * NPRE; i += 256)
        hl[i / NPRE][i % NPRE] = pre[(size_t)t * NB * NPRE + i];
    __syncthreads();
    int j = threadIdx.x;
    float acc[NB];
#pragma unroll
    for (int b = 0; b < NB; b++) acc[b] = 0.0f;
    for (int k = 0; k < NPRE; k++) {
        float w = w2[j * NPRE + k];
#pragma unroll
        for (int b = 0; b < NB; b++) acc[b] += hl[b][k] * w;
    }
    for (int b = 0; b < NB; b++) pre[((size_t)t * NB + b) * NPRE + j] = fmaxf(acc[b], 0.0f);
}

// processed_memory TRANSPOSED: pmt[b][a][t]
__global__ __launch_bounds__(128) void pmt_kernel(const float* __restrict__ mem,
                                                  const float* __restrict__ mw,
                                                  float* __restrict__ pmt) {
    int b = blockIdx.y, t0 = blockIdx.x * 4;
    __shared__ float ml[4][NENC];
    for (int i = threadIdx.x; i < 4 * NENC; i += 128)
        ml[i / NENC][i % NENC] = mem[((size_t)b * TIN + t0 + i / NENC) * NENC + (i % NENC)];
    __syncthreads();
    int a = threadIdx.x;
    float acc[4] = {0, 0, 0, 0};
    for (int e = 0; e < NENC; e++) {
        float w = mw[a * NENC + e];
#pragma unroll
        for (int tt = 0; tt < 4; tt++) acc[tt] += ml[tt][e] * w;
    }
    *(float4*)&pmt[((size_t)b * NATT + a) * TIN + t0] = make_float4(acc[0], acc[1], acc[2], acc[3]);
}

// ---------------- persistent kernel ----------------
struct Params {
    const float* memory; const int* mlen;
    const float* awih; const float* awhh; const float* abih; const float* abhh;
    const float* qw; const float* vw; const float* wc; const float* ldw;
    const float* dwih; const float* dwhh; const float* dbih; const float* dbhh;
    const float* pjw; const float* pjb; const float* gtw; const float* gtb;
    float* ws; float* out;
};

// round-7 barrier verbatim (two-stage monotone; 8 per-XCD invalidators)
__device__ __forceinline__ void gbar(unsigned* bar, unsigned n, bool am_inv) {
    asm volatile("s_waitcnt vmcnt(0)" ::: "memory");
    __syncthreads();
    if (threadIdx.x == 0) {
        unsigned* grp   = bar + ((blockIdx.x >> 5) << 5);
        unsigned* root  = bar + 256;
        unsigned* root2 = bar + 320;
        unsigned old = __hip_atomic_fetch_add(grp, 1u, __ATOMIC_RELAXED, __HIP_MEMORY_SCOPE_AGENT);
        if (old + 1u == (n << 5))
            __hip_atomic_fetch_add(root, 1u, __ATOMIC_RELAXED, __HIP_MEMORY_SCOPE_AGENT);
        while (__hip_atomic_load(root, __ATOMIC_RELAXED, __HIP_MEMORY_SCOPE_AGENT) < (n << 3))
            __builtin_amdgcn_s_sleep(1);
        unsigned ninv = __hip_atomic_load(bar + 416, __ATOMIC_RELAXED, __HIP_MEMORY_SCOPE_AGENT);
        if (am_inv) {
            asm volatile("buffer_wbl2 sc1\n\t"
                         "s_waitcnt vmcnt(0)\n\t"
                         "buffer_inv sc0 sc1\n\t"
                         "s_waitcnt vmcnt(0)" ::: "memory");
            __hip_atomic_fetch_add(root2, 1u, __ATOMIC_RELAXED, __HIP_MEMORY_SCOPE_AGENT);
        }
        while (__hip_atomic_load(root2, __ATOMIC_RELAXED, __HIP_MEMORY_SCOPE_AGENT) < n * ninv)
            __builtin_amdgcn_s_sleep(1);
        asm volatile("buffer_inv sc0" ::: "memory");
    }
    __syncthreads();
}

// ---- 8-col register-blocked z accumulate ----
// wave covers cols {cbase + 2j + colh}, j=0..3; lanes = colh(1)*32 + kpos(0..31)
// acc[j][b] accumulates K-chunk kpos*4..+3 per tick. Explicit 8-wide x batches
// force >=8 outstanding loads (round-7 was MLP-starved at 100 VGPRs).
__device__ __forceinline__ void zacc8(const float* __restrict__ wbase, int wstride,
                                      const float* __restrict__ x, int xs,
                                      int nticks, int kpos, float acc[4][32]) {
    for (int tk = 0; tk < nticks; ++tk) {
        int k = tk * 128 + kpos * 4;
        float4 w0 = *(const float4*)(wbase + k);
        float4 w1 = *(const float4*)(wbase + 2 * wstride + k);
        float4 w2 = *(const float4*)(wbase + 4 * wstride + k);
        float4 w3 = *(const float4*)(wbase + 6 * wstride + k);
        const float* xk = x + k;
#pragma unroll
        for (int bb = 0; bb < 4; ++bb) {
            const float* xb = xk + (size_t)(bb * 8) * xs;
            float4 v0 = *(const float4*)(xb);
            float4 v1 = *(const float4*)(xb + (size_t)1 * xs);
            float4 v2 = *(const float4*)(xb + (size_t)2 * xs);
            float4 v3 = *(const float4*)(xb + (size_t)3 * xs);
            float4 v4 = *(const float4*)(xb + (size_t)4 * xs);
            float4 v5 = *(const float4*)(xb + (size_t)5 * xs);
            float4 v6 = *(const float4*)(xb + (size_t)6 * xs);
            float4 v7 = *(const float4*)(xb + (size_t)7 * xs);
            float4 xv[8] = {v0, v1, v2, v3, v4, v5, v6, v7};
#pragma unroll
            for (int i = 0; i < 8; ++i) {
                int b = bb * 8 + i;
                acc[0][b] = fmaf(w0.x, xv[i].x, acc[0][b]); acc[0][b] = fmaf(w0.y, xv[i].y, acc[0][b]);
                acc[0][b] = fmaf(w0.z, xv[i].z, acc[0][b]); acc[0][b] = fmaf(w0.w, xv[i].w, acc[0][b]);
                acc[1][b] = fmaf(w1.x, xv[i].x, acc[1][b]); acc[1][b] = fmaf(w1.y, xv[i].y, acc[1][b]);
                acc[1][b] = fmaf(w1.z, xv[i].z, acc[1][b]); acc[1][b] = fmaf(w1.w, xv[i].w, acc[1][b]);
                acc[2][b] = fmaf(w2.x, xv[i].x, acc[2][b]); acc[2][b] = fmaf(w2.y, xv[i].y, acc[2][b]);
                acc[2][b] = fmaf(w2.z, xv[i].z, acc[2][b]); acc[2][b] = fmaf(w2.w, xv[i].w, acc[2][b]);
                acc[3][b] = fmaf(w3.x, xv[i].x, acc[3][b]); acc[3][b] = fmaf(w3.y, xv[i].y, acc[3][b]);
                acc[3][b] = fmaf(w3.z, xv[i].z, acc[3][b]); acc[3][b] = fmaf(w3.w, xv[i].w, acc[3][b]);
            }
        }
    }
}

__device__ __forceinline__ void zred_write(float acc[4][32], int kpos, int colh,
                                           float* zsl, int cbase) {
#pragma unroll
    for (int j = 0; j < 4; ++j)
#pragma unroll
        for (int b = 0; b < 32; ++b) {
            float v = acc[j][b];
            v += __shfl_xor(v, 1); v += __shfl_xor(v, 2); v += __shfl_xor(v, 4);
            v += __shfl_xor(v, 8); v += __shfl_xor(v, 16);
            if (kpos == 0) st_wt(&zsl[((size_t)b << 12) + cbase + 2 * j + colh], v);
        }
}

#define ZLANES int wv = tid >> 6, lane = tid & 63, colh = lane >> 5, kpos = lane & 31; \
    float acc[4][32]; \
    _Pragma("unroll") for (int j = 0; j < 4; ++j) _Pragma("unroll") for (int b = 0; b < 32; ++b) acc[j][b] = 0.f;

// zd-main task tau in [0,128): cols (tau>>1)*64..+64, K-half = tau&1
__device__ void zd_main_task(const Params& p, int tau, int tid) {
    ZLANES
    int cbase = (tau >> 1) * 64 + wv * 8;
    if ((tau & 1) == 0) {
        zacc8(p.dwih + (size_t)(cbase + colh) * 1536, 1536, p.ws + WS_AH, NU, 8, kpos, acc);
        zred_write(acc, kpos, colh, p.ws + WS_ZD0, cbase);
    } else {
        zacc8(p.dwhh + (size_t)(cbase + colh) * 1024, 1024, p.ws + WS_DH, NU, 8, kpos, acc);
        zred_write(acc, kpos, colh, p.ws + WS_ZD1, cbase);
    }
}

// za-main task tau in [0,64): cols tau*64..+64 (pre(ts) + hh parts)
__device__ void za_main_task(const Params& p, int tau, int ts, int tid) {
    ZLANES
    int cbase = tau * 64 + wv * 8;
    zacc8(p.awih + (size_t)(cbase + colh) * 768, 768,
          p.ws + WS_PRE + (size_t)ts * NB * NPRE, NPRE, 2, kpos, acc);
    zacc8(p.awhh + (size_t)(cbase + colh) * 1024, 1024, p.ws + WS_AH, NU, 8, kpos, acc);
    zred_write(acc, kpos, colh, p.ws + WS_ZA0, cbase);
}

// z-actx task tau in [0,128): tau<64 -> zd-actx; else za-actx
__device__ void z_actx_task(const Params& p, int tau, int tid) {
    ZLANES
    if (tau < 64) {
        int cbase = tau * 64 + wv * 8;
        zacc8(p.dwih + (size_t)(cbase + colh) * 1536 + 1024, 1536,
              p.ws + WS_ACTX, NENC, 4, kpos, acc);
        zred_write(acc, kpos, colh, p.ws + WS_ZDA, cbase);
    } else {
        int cbase = (tau - 64) * 64 + wv * 8;
        zacc8(p.awih + (size_t)(cbase + colh) * 768 + 256, 768,
              p.ws + WS_ACTX, NENC, 4, kpos, acc);
        zred_write(acc, kpos, colh, p.ws + WS_ZAA, cbase);
    }
}

// attn (no ctx): conv31 -> dense -> tanh -> vdot -> mask -> softmax -> aw
__device__ void attn_block(const Params& p, int b, int step, int tid, float* sm) {
    float* ws = p.ws;
    float* awl = sm, *cuml = sm + 512, *pql = sm + 1024, *red = sm + 1152;
    awl[tid] = ws[WS_AW + b * 512 + tid];
    cuml[tid] = ws[WS_AWCUM + b * 512 + tid];
    if (tid < NATT) pql[tid] = ws[WS_PQ + b * NATT + tid];
    __syncthreads();
    int t = tid;
    float loc[32];
#pragma unroll
    for (int f = 0; f < 32; ++f) loc[f] = 0.f;
    for (int d = 0; d < 31; ++d) {
        int tp = t + d - 15;
        int tc = min(max(tp, 0), 511);
        bool ok = (tp >= 0) && (tp < 512);
        float a_ = ok ? awl[tc] : 0.f;
        float c_ = ok ? cuml[tc] : 0.f;
#pragma unroll
        for (int f = 0; f < 32; ++f)
            loc[f] = fmaf(a_, p.wc[f * 62 + d], fmaf(c_, p.wc[f * 62 + 31 + d], loc[f]));
    }
    float e = 0.f;
    const float* pmt = ws + WS_PM + (size_t)b * NATT * TIN + t;
    for (int a = 0; a < NATT; ++a) {
        float s = pql[a] + pmt[(size_t)a * TIN];
#pragma unroll
        for (int f = 0; f < 32; ++f) s = fmaf(loc[f], p.ldw[a * 32 + f], s);
        e = fmaf(ftanh(s), p.vw[a], e);
    }
    if (t >= p.mlen[b]) e = -3.0e38f;
    float m = e;
#pragma unroll
    for (int sh = 1; sh <= 32; sh <<= 1) m = fmaxf(m, __shfl_xor(m, sh));
    if ((tid & 63) == 0) red[tid >> 6] = m;
    __syncthreads();
    m = fmaxf(fmaxf(fmaxf(red[0], red[1]), fmaxf(red[2], red[3])),
              fmaxf(fmaxf(red[4], red[5]), fmaxf(red[6], red[7])));
    float pv = __expf(e - m);
    float ss = pv;
#pragma unroll
    for (int sh = 1; sh <= 32; sh <<= 1) ss += __shfl_xor(ss, sh);
    if ((tid & 63) == 0) red[8 + (tid >> 6)] = ss;
    __syncthreads();
    float tot = red[8] + red[9] + red[10] + red[11] + red[12] + red[13] + red[14] + red[15];
    float aw = pv / tot;
    st_wt(&ws[WS_AW + b * 512 + t], aw);              // cross-block (ctx reads)
    ws[WS_AWCUM + b * 512 + t] += aw;                 // private
    p.out[OUT_ALIGN + ((size_t)b * TOUT + step) * TIN + t] = aw;
}

// ctx: 4 blocks per b (e-quarters), 4 independent t-chains per thread
__device__ void ctx_block(const Params& p, int bid, int tid, float* sm) {
    int b = bid >> 2, ec = bid & 3;
    float* ws = p.ws;
    float* awl = sm; float* part = sm + 512;
    awl[tid] = ws[WS_AW + b * 512 + tid];
    __syncthreads();
    int e = tid & 127, tq = tid >> 7;
    const float* mb = p.memory + (size_t)b * TIN * NENC + ec * 128 + e;
    int t0 = tq * 128;
    float a0 = 0.f, a1 = 0.f, a2 = 0.f, a3 = 0.f;
#pragma unroll 8
    for (int tt = 0; tt < 128; tt += 4) {
        a0 = fmaf(awl[t0 + tt],     mb[(size_t)(t0 + tt)     * NENC], a0);
        a1 = fmaf(awl[t0 + tt + 1], mb[(size_t)(t0 + tt + 1) * NENC], a1);
        a2 = fmaf(awl[t0 + tt + 2], mb[(size_t)(t0 + tt + 2) * NENC], a2);
        a3 = fmaf(awl[t0 + tt + 3], mb[(size_t)(t0 + tt + 3) * NENC], a3);
    }
    part[tq * 128 + e] = (a0 + a1) + (a2 + a3);
    __syncthreads();
    if (tid < 128)
        st_wt(&ws[WS_ACTX + b * NENC + ec * 128 + tid],
              part[tid] + part[128 + tid] + part[256 + tid] + part[384 + tid]);
}

__device__ void agates_pq(const Params& p, int b, int tid, float* sm) {
    float* ahl = sm;
    float* ws = p.ws;
    float* AH = ws + WS_AH + (size_t)b * NU;
    float* AC = ws + WS_AC + (size_t)b * NU;
    const float* Z0 = ws + WS_ZA0 + (size_t)b * NG;
    const float* Z1 = ws + WS_ZAA + (size_t)b * NG;
    for (int u = tid; u < NU; u += NTHR) {
        float zi = Z0[u]          + Z1[u]          + p.abih[u]          + p.abhh[u];
        float zf = Z0[NU + u]     + Z1[NU + u]     + p.abih[NU + u]     + p.abhh[NU + u];
        float zg = Z0[2 * NU + u] + Z1[2 * NU + u] + p.abih[2 * NU + u] + p.abhh[2 * NU + u];
        float zo = Z0[3 * NU + u] + Z1[3 * NU + u] + p.abih[3 * NU + u] + p.abhh[3 * NU + u];
        float c = fsigm(zf) * AC[u] + fsigm(zi) * ftanh(zg);
        float h = fsigm(zo) * ftanh(c);
        AC[u] = c;
        st_wt(&AH[u], h);
        ahl[u] = h;
    }
    __syncthreads();
    int a = tid >> 2, q = tid & 3;
    const float* qr = p.qw + (size_t)a * NU + q * 256;
    const float* h4 = ahl + q * 256;
    float s = 0.f;
#pragma unroll
    for (int k4 = 0; k4 < 64; k4++) {
        float4 hv = *(const float4*)(h4 + k4 * 4);
        float4 wv = *(const float4*)(qr + k4 * 4);
        s = fmaf(hv.x, wv.x, s); s = fmaf(hv.y, wv.y, s);
        s = fmaf(hv.z, wv.z, s); s = fmaf(hv.w, wv.w, s);
    }
    s += __shfl_xor(s, 1); s += __shfl_xor(s, 2);
    if (q == 0) st_wt(&ws[WS_PQ + b * NATT + a], s);
    __syncthreads();
}

__device__ void dgates_proj(const Params& p, int b, int t, int tid, float* sm) {
    float* dhc = sm;
    float* ws = p.ws;
    float* DH = ws + WS_DH + (size_t)b * NU;
    float* DC = ws + WS_DC + (size_t)b * NU;
    const float* Z0 = ws + WS_ZD0 + (size_t)b * NG;
    const float* Z1 = ws + WS_ZD1 + (size_t)b * NG;
    const float* Z2 = ws + WS_ZDA + (size_t)b * NG;
    for (int u = tid; u < NU; u += NTHR) {
        float zi = Z0[u]          + Z1[u]          + Z2[u]          + p.dbih[u]          + p.dbhh[u];
        float zf = Z0[NU + u]     + Z1[NU + u]     + Z2[NU + u]     + p.dbih[NU + u]     + p.dbhh[NU + u];
        float zg = Z0[2 * NU + u] + Z1[2 * NU + u] + Z2[2 * NU + u] + p.dbih[2 * NU + u] + p.dbhh[2 * NU + u];
        float zo = Z0[3 * NU + u] + Z1[3 * NU + u] + Z2[3 * NU + u] + p.dbih[3 * NU + u] + p.dbhh[3 * NU + u];
        float c = fsigm(zf) * DC[u] + fsigm(zi) * ftanh(zg);
        float h = fsigm(zo) * ftanh(c);
        DC[u] = c;
        st_wt(&DH[u], h);
        dhc[u] = h;
    }
    for (int i = tid; i < NENC; i += NTHR) dhc[NU + i] = ws[WS_ACTX + b * NENC + i];
    __syncthreads();
    int col = tid >> 2, q = tid & 3;
    if (col < 81) {
        const float* wr = (col < 80) ? (p.pjw + (size_t)col * 1536) : p.gtw;
        const float* d4 = dhc + q * 384;
        const float* w4 = wr + q * 384;
        float s = 0.f;
#pragma unroll
        for (int k4 = 0; k4 < 96; k4++) {
            float4 hv = *(const float4*)(d4 + k4 * 4);
            float4 wv = *(const float4*)(w4 + k4 * 4);
            s = fmaf(hv.x, wv.x, s); s = fmaf(hv.y, wv.y, s);
            s = fmaf(hv.z, wv.z, s); s = fmaf(hv.w, wv.w, s);
        }
        s += __shfl_xor(s, 1); s += __shfl_xor(s, 2);
        if (q == 0) {
            s += (col < 80) ? p.pjb[col] : p.gtb[0];
            if (col < 80) p.out[((size_t)b * NMEL + col) * TOUT + t] = s;
            else          p.out[(size_t)NB * NMEL * TOUT + (size_t)b * TOUT + t] = s;
        }
    }
    __syncthreads();
}

__global__ __launch_bounds__(NTHR, 2) void persist_kernel(Params p) {
    __shared__ float sm[1664];
    int tid = threadIdx.x, bid = blockIdx.x;
    unsigned* bar = (unsigned*)(p.ws + WS_BAR);
    unsigned nb_ = 0;
    bool am_inv = false;

    if (tid == 0) {
        unsigned xcd;
        asm volatile("s_getreg_b32 %0, hwreg(HW_REG_XCC_ID)" : "=s"(xcd));
        unsigned old = __hip_atomic_fetch_add(bar + 352 + (xcd & 63u), 1u,
                                              __ATOMIC_RELAXED, __HIP_MEMORY_SCOPE_AGENT);
        if (old == 0u) {
            __hip_atomic_fetch_add(bar + 416, 1u, __ATOMIC_RELAXED, __HIP_MEMORY_SCOPE_AGENT);
            am_inv = true;
        }
    }

    // prologue: za-main(0) (ZAA zeroed -> actx(-1)=0), then agates+pq(0)
    if (bid < 64) za_main_task(p, bid, 0, tid);
    ++nb_; gbar(bar, nb_, am_inv);
    if (bid < 32) agates_pq(p, bid, tid, sm);
    ++nb_; gbar(bar, nb_, am_inv);

    for (int t = 0; t < TOUT; ++t) {
        bool more = (t + 1 < TOUT);
        // P1: attn(t) [32] || zd-main (128 tasks)
        if (bid < 32) attn_block(p, bid, t, tid, sm);
        else if (bid - 32 < 128) zd_main_task(p, bid - 32, tid);
        ++nb_; gbar(bar, nb_, am_inv);
        // P2: ctx(t) [128] || za-main(t+1) (64 tasks)
        if (bid < 128) ctx_block(p, bid, tid, sm);
        else if (more && bid - 128 < 64) za_main_task(p, bid - 128, t + 1, tid);
        ++nb_; gbar(bar, nb_, am_inv);
        // P3: z-actx: zd(t) [64] + za(t+1) [64]
        if (bid < 64) z_actx_task(p, bid, tid);
        else if (more && bid < 128) z_actx_task(p, bid, tid);
        ++nb_; gbar(bar, nb_, am_inv);
        // P4: dgates+proj(t) [32] || agates+pq(t+1) [32]
        if (bid < 32) dgates_proj(p, bid, t, tid, sm);
        else if (more && bid < 64) agates_pq(p, bid - 32, tid, sm);
        ++nb_; gbar(bar, nb_, am_inv);
    }

    // self-reset barrier region
    if (tid == 0) {
        unsigned* done = bar + 288;
        unsigned old = __hip_atomic_fetch_add(done, 1u, __ATOMIC_RELAXED, __HIP_MEMORY_SCOPE_AGENT);
        if (old == NBLK - 1u) {
#pragma unroll
            for (int i = 0; i < 8; ++i)
                __hip_atomic_store(bar + i * 32, 0u, __ATOMIC_RELAXED, __HIP_MEMORY_SCOPE_AGENT);
            __hip_atomic_store(bar + 256, 0u, __ATOMIC_RELAXED, __HIP_MEMORY_SCOPE_AGENT);
            __hip_atomic_store(bar + 320, 0u, __ATOMIC_RELAXED, __HIP_MEMORY_SCOPE_AGENT);
            for (int i = 0; i < 64; ++i)
                __hip_atomic_store(bar + 352 + i, 0u, __ATOMIC_RELAXED, __HIP_MEMORY_SCOPE_AGENT);
            __hip_atomic_store(bar + 416, 0u, __ATOMIC_RELAXED, __HIP_MEMORY_SCOPE_AGENT);
            __hip_atomic_store(bar + 288, 0u, __ATOMIC_RELAXED, __HIP_MEMORY_SCOPE_AGENT);
        }
    }
}

extern "C" void kernel_launch(void* const* d_in, const int* in_sizes, int n_in,
                              void* d_out, int out_size, void* d_ws, size_t ws_size,
                              hipStream_t stream) {
    const float* memory = (const float*)d_in[0];
    const float* dec    = (const float*)d_in[1];
    const int*   mlen   = (const int*)d_in[2];
    const float* pw1    = (const float*)d_in[3];
    const float* pw2    = (const float*)d_in[4];
    const float* awih   = (const float*)d_in[5];
    const float* awhh   = (const float*)d_in[6];
    const float* abih   = (const float*)d_in[7];
    const float* abhh   = (const float*)d_in[8];
    const float* qw     = (const float*)d_in[9];
    const float* mw     = (const float*)d_in[10];
    const float* vw     = (const float*)d_in[11];
    const float* wc     = (const float*)d_in[12];
    const float* ldw    = (const float*)d_in[13];
    const float* dwih   = (const float*)d_in[14];
    const float* dwhh   = (const float*)d_in[15];
    const float* dbih   = (const float*)d_in[16];
    const float* dbhh   = (const float*)d_in[17];
    const float* pjw    = (const float*)d_in[18];
    const float* pjb    = (const float*)d_in[19];
    const float* gtw    = (const float*)d_in[20];
    const float* gtb    = (const float*)d_in[21];
    float* ws  = (float*)d_ws;
    float* out = (float*)d_out;

    hipMemsetAsync(d_ws, 0, WS_ZERO_BYTES, stream);
    prenet1_kernel<<<TOUT, 256, 0, stream>>>(dec, pw1, ws + WS_PRE);
    prenet2_kernel<<<TOUT, 256, 0, stream>>>(pw2, ws + WS_PRE);
    pmt_kernel<<<dim3(TIN / 4, NB), 128, 0, stream>>>(memory, mw, ws + WS_PM);

    Params pp = { memory, mlen, awih, awhh, abih, abhh, qw, vw, wc, ldw,
                  dwih, dwhh, dbih, dbhh, pjw, pjb, gtw, gtb, ws, out };
    void* args[] = { &pp };
    hipLaunchCooperativeKernel((const void*)persist_kernel, dim3(NBLK), dim3(NTHR),
                               args, 0, stream);
}

// Round 9
// 96127.582 us; speedup vs baseline: 3.9930x; 1.7919x over previous
//
#include <hip/hip_runtime.h>
#include <math.h>

#define NB 32
#define TIN 512
#define TOUT 512
#define NENC 512
#define NATT 128
#define NU 1024
#define NG 4096
#define NPRE 256
#define NMEL 80

// ws offsets (floats)
#define WS_AH    0u
#define WS_AC    32768u
#define WS_DH    65536u
#define WS_DC    98304u
#define WS_ACTX  131072u
#define WS_AW    147456u
#define WS_AWCUM 163840u
#define WS_E     180224u
#define WS_PQ    196608u
#define WS_ZD    200704u                    // 20*32*4096
#define WS_ZA    2822144u                   // 14*32*4096
#define WS_PM    4657152u                   // 32*512*128 [b][t][a]
#define WS_PRE   6754304u                   // 513*32*256 (row 512 = zeros)
#define WS_STATE_ZERO_BYTES (200704u * 4u)
#define OUT_ALIGN ((size_t)NB * NMEL * TOUT + (size_t)NB * TOUT)

__device__ __forceinline__ float fsigm(float x) { return 1.f / (1.f + __expf(-x)); }
__device__ __forceinline__ float ftanh(float x) { return 1.f - 2.f / (__expf(2.f * x) + 1.f); }

// ---------------- setup kernels (round-1 proven) ----------------
__global__ __launch_bounds__(256) void prenet1_kernel(const float* __restrict__ dec,
                                                      const float* __restrict__ w1,
                                                      float* __restrict__ pre) {
    int t = blockIdx.x;
    __shared__ float xl[NB][NMEL];
    for (int i = threadIdx.x; i < NB * NMEL; i += 256) {
        int b = i / NMEL, m = i % NMEL;
        xl[b][m] = (t == 0) ? 0.0f : dec[(b * NMEL + m) * TOUT + (t - 1)];
    }
    __syncthreads();
    int j = threadIdx.x;
    float acc[NB];
#pragma unroll
    for (int b = 0; b < NB; b++) acc[b] = 0.0f;
    for (int m = 0; m < NMEL; m++) {
        float w = w1[j * NMEL + m];
#pragma unroll
        for (int b = 0; b < NB; b++) acc[b] += xl[b][m] * w;
    }
    for (int b = 0; b < NB; b++) pre[((size_t)t * NB + b) * NPRE + j] = fmaxf(acc[b], 0.0f);
}

__global__ __launch_bounds__(256) void prenet2_kernel(const float* __restrict__ w2,
                                                      float* __restrict__ pre) {
    int t = blockIdx.x;
    __shared__ float hl[NB][NPRE];
    for (int i = threadIdx.x; i < NB * NPRE; i += 256)
        hl[i / NPRE][i % NPRE] = pre[(size_t)t * NB * NPRE + i];
    __syncthreads();
    int j = threadIdx.x;
    float acc[NB];
#pragma unroll
    for (int b = 0; b < NB; b++) acc[b] = 0.0f;
    for (int k = 0; k < NPRE; k++) {
        float w = w2[j * NPRE + k];
#pragma unroll
        for (int b = 0; b < NB; b++) acc[b] += hl[b][k] * w;
    }
    for (int b = 0; b < NB; b++) pre[((size_t)t * NB + b) * NPRE + j] = fmaxf(acc[b], 0.0f);
}

__global__ __launch_bounds__(128) void pm_kernel(const float* __restrict__ mem,
                                                 const float* __restrict__ mw,
                                                 float* __restrict__ pm) {
    int b = blockIdx.y, t0 = blockIdx.x * 4;
    __shared__ float ml[4][NENC];
    for (int i = threadIdx.x; i < 4 * NENC; i += 128)
        ml[i / NENC][i % NENC] = mem[((size_t)b * TIN + t0 + i / NENC) * NENC + (i % NENC)];
    __syncthreads();
    int a = threadIdx.x;
    float acc[4] = {0, 0, 0, 0};
    for (int e = 0; e < NENC; e++) {
        float w = mw[a * NENC + e];
#pragma unroll
        for (int tt = 0; tt < 4; tt++) acc[tt] += ml[tt][e] * w;
    }
    for (int tt = 0; tt < 4; tt++)
        pm[((size_t)b * TIN + t0 + tt) * NATT + a] = acc[tt];
}

// ---------------- fused z GEMV (both LSTMs), r1 lane=column layout ----------------
// slice s: 0-7 dwih@AH | 8-11 dwih@ACTX | 12-19 dwhh@DH |
//          20-21 awih@PRE(ts) | 22-25 awih@ACTX | 26-33 awhh@AH
// Per thread: one column, one 128-wide K chunk, all 32 batches.
// Weight reads: per-lane rows (64 lines in flight per load instr — intentional).
// x reads: wave-uniform -> scalar s_loads.
__global__ __launch_bounds__(256) void z_fused_kernel(
        const float* __restrict__ dwih, const float* __restrict__ dwhh,
        const float* __restrict__ awih, const float* __restrict__ awhh,
        const float* __restrict__ ws_base, const float* __restrict__ pre_t,
        float* __restrict__ zd, float* __restrict__ za, int sbase) {
    int col = blockIdx.x * 256 + threadIdx.x;
    int s = blockIdx.y + sbase;
    const float* ah   = ws_base + WS_AH;
    const float* dh   = ws_base + WS_DH;
    const float* actx = ws_base + WS_ACTX;
    const float* W; const float* x; int xs;
    if (s < 8)       { W = dwih + (size_t)col * 1536 + s * 128;              x = ah + s * 128;          xs = NU;   }
    else if (s < 12) { W = dwih + (size_t)col * 1536 + 1024 + (s - 8) * 128; x = actx + (s - 8) * 128;  xs = NENC; }
    else if (s < 20) { W = dwhh + (size_t)col * 1024 + (s - 12) * 128;       x = dh + (s - 12) * 128;   xs = NU;   }
    else if (s < 22) { W = awih + (size_t)col * 768 + (s - 20) * 128;        x = pre_t + (s - 20) * 128; xs = NPRE; }
    else if (s < 26) { W = awih + (size_t)col * 768 + 256 + (s - 22) * 128;  x = actx + (s - 22) * 128; xs = NENC; }
    else             { W = awhh + (size_t)col * 1024 + (s - 26) * 128;       x = ah + (s - 26) * 128;   xs = NU;   }

    float acc[NB];
#pragma unroll
    for (int b = 0; b < NB; b++) acc[b] = 0.0f;
    for (int k4 = 0; k4 < 32; k4++) {
        float4 w4 = *(const float4*)(W + k4 * 4);
#pragma unroll
        for (int b = 0; b < NB; b++) {
            float4 x4 = *(const float4*)(x + (size_t)b * xs + k4 * 4);  // wave-uniform -> scalar
            acc[b] = fmaf(w4.x, x4.x, acc[b]);
            acc[b] = fmaf(w4.y, x4.y, acc[b]);
            acc[b] = fmaf(w4.z, x4.z, acc[b]);
            acc[b] = fmaf(w4.w, x4.w, acc[b]);
        }
    }
    float* zp = ((s < 20) ? (zd + (size_t)s * NB * NG) : (za + (size_t)(s - 20) * NB * NG)) + col;
#pragma unroll
    for (int b = 0; b < NB; b++) zp[(size_t)b * NG] = acc[b];
}

// ---------------- r1-proven energies ----------------
__global__ __launch_bounds__(128) void energies_kernel(const float* __restrict__ pm,
                                                       const float* __restrict__ wc,
                                                       const float* __restrict__ ldw,
                                                       const float* __restrict__ vw,
                                                       const int* __restrict__ mlen,
                                                       const float* __restrict__ ws_aw,
                                                       const float* __restrict__ ws_awcum,
                                                       const float* __restrict__ ws_pq,
                                                       float* __restrict__ ws_e) {
    int b = blockIdx.y, tc = blockIdx.x;
    int tt = threadIdx.x & 31, sub = threadIdx.x >> 5;
    int t = tc * 32 + tt;
    __shared__ float awl[TIN], cuml[TIN], locl[32][33], pql[NATT], ep[32][4];
    for (int i = threadIdx.x; i < TIN; i += 128) {
        awl[i]  = ws_aw[b * TIN + i];
        cuml[i] = ws_awcum[b * TIN + i];
    }
    for (int i = threadIdx.x; i < NATT; i += 128) pql[i] = ws_pq[b * NATT + i];
    __syncthreads();
    for (int f = sub * 8; f < sub * 8 + 8; f++) {
        float s = 0.0f;
        const float* wA = wc + f * 62;
        const float* wB = wA + 31;
        for (int d = 0; d < 31; d++) {
            int tp = t + d - 15;
            if (tp >= 0 && tp < TIN) s += awl[tp] * wA[d] + cuml[tp] * wB[d];
        }
        locl[tt][f] = s;
    }
    __syncthreads();
    float acc = 0.0f;
    const float* pmb = pm + ((size_t)b * TIN + t) * NATT;
    for (int a = sub * 32; a < sub * 32 + 32; a++) {
        float s = pql[a] + pmb[a];
        const float* lw = ldw + a * 32;
#pragma unroll
        for (int f = 0; f < 32; f++) s += locl[tt][f] * lw[f];
        acc += tanhf(s) * vw[a];
    }
    ep[tt][sub] = acc;
    __syncthreads();
    if (sub == 0) {
        float ev = ep[tt][0] + ep[tt][1] + ep[tt][2] + ep[tt][3];
        if (t >= mlen[b]) ev = -3.0e38f;
        ws_e[b * TIN + t] = ev;
    }
}

// ---------------- r1-proven softmax + context ----------------
__global__ __launch_bounds__(256) void softmax_ctx_kernel(const float* __restrict__ mem,
                                                          const float* __restrict__ E,
                                                          float* __restrict__ AW,
                                                          float* __restrict__ AWCUM,
                                                          float* __restrict__ ACTX,
                                                          float* __restrict__ out_align, int step) {
    int b = blockIdx.y, ec = blockIdx.x;
    __shared__ float el[TIN];
    __shared__ float red[256];
    __shared__ float part[4][64];
    const float* Eb = E + b * TIN;
    for (int i = threadIdx.x; i < TIN; i += 256) el[i] = Eb[i];
    __syncthreads();
    red[threadIdx.x] = fmaxf(el[threadIdx.x], el[threadIdx.x + 256]);
    __syncthreads();
    for (int s = 128; s > 0; s >>= 1) {
        if (threadIdx.x < s) red[threadIdx.x] = fmaxf(red[threadIdx.x], red[threadIdx.x + s]);
        __syncthreads();
    }
    float mx = red[0];
    __syncthreads();
    float p0 = __expf(el[threadIdx.x] - mx), p1 = __expf(el[threadIdx.x + 256] - mx);
    el[threadIdx.x] = p0; el[threadIdx.x + 256] = p1;
    red[threadIdx.x] = p0 + p1;
    __syncthreads();
    for (int s = 128; s > 0; s >>= 1) {
        if (threadIdx.x < s) red[threadIdx.x] += red[threadIdx.x + s];
        __syncthreads();
    }
    float inv = 1.0f / red[0];
    int ei = ec * 64 + (threadIdx.x & 63), tp4 = threadIdx.x >> 6;
    float acc = 0.0f;
    const float* mb = mem + (size_t)b * TIN * NENC + ei;
    for (int t = tp4 * 128; t < tp4 * 128 + 128; t++) acc += el[t] * mb[(size_t)t * NENC];
    part[tp4][threadIdx.x & 63] = acc;
    __syncthreads();
    if (threadIdx.x < 64) {
        float ctx = (part[0][threadIdx.x] + part[1][threadIdx.x] +
                     part[2][threadIdx.x] + part[3][threadIdx.x]) * inv;
        ACTX[b * NENC + ec * 64 + threadIdx.x] = ctx;
    }
    if (ec == 0) {
        for (int i = threadIdx.x; i < TIN; i += 256) {
            float a_ = el[i] * inv;
            AW[b * TIN + i] = a_;
            AWCUM[b * TIN + i] += a_;
            out_align[((size_t)b * TOUT + step) * TIN + i] = a_;
        }
    }
}

// ---------------- fused gates: dgates+proj(t) [blocks 0-31] || agates+pq(t+1) [32-63] ----------------
__global__ __launch_bounds__(512) void gates_kernel(
        const float* __restrict__ abih, const float* __restrict__ abhh,
        const float* __restrict__ qw,
        const float* __restrict__ dbih, const float* __restrict__ dbhh,
        const float* __restrict__ pjw, const float* __restrict__ pjb,
        const float* __restrict__ gtw, const float* __restrict__ gtb,
        float* __restrict__ ws, float* __restrict__ out, int t) {
    __shared__ float sm[NU + NENC];
    int tid = threadIdx.x, bid = blockIdx.x;
    if (bid < 32) {
        if (t < 0) return;
        int b = bid;
        float* DH = ws + WS_DH + (size_t)b * NU;
        float* DC = ws + WS_DC + (size_t)b * NU;
        for (int u = tid; u < NU; u += 512) {
            float zi = dbih[u]          + dbhh[u];
            float zf = dbih[NU + u]     + dbhh[NU + u];
            float zg = dbih[2 * NU + u] + dbhh[2 * NU + u];
            float zo = dbih[3 * NU + u] + dbhh[3 * NU + u];
            for (int s = 0; s < 20; s++) {
                const float* z = ws + WS_ZD + ((size_t)s * NB + b) * NG;
                zi += z[u]; zf += z[NU + u]; zg += z[2 * NU + u]; zo += z[3 * NU + u];
            }
            float c = fsigm(zf) * DC[u] + fsigm(zi) * ftanh(zg);
            float h = fsigm(zo) * ftanh(c);
            DC[u] = c; DH[u] = h; sm[u] = h;
        }
        for (int i = tid; i < NENC; i += 512) sm[NU + i] = ws[WS_ACTX + b * NENC + i];
        __syncthreads();
        int col = tid >> 2, q = tid & 3;
        if (col < 81) {
            const float* wr = (col < 80) ? (pjw + (size_t)col * 1536) : gtw;
            const float* d4 = sm + q * 384;
            const float* w4 = wr + q * 384;
            float s = 0.f;
#pragma unroll
            for (int k4 = 0; k4 < 96; k4++) {
                float4 hv = *(const float4*)(d4 + k4 * 4);
                float4 wv = *(const float4*)(w4 + k4 * 4);
                s = fmaf(hv.x, wv.x, s); s = fmaf(hv.y, wv.y, s);
                s = fmaf(hv.z, wv.z, s); s = fmaf(hv.w, wv.w, s);
            }
            s += __shfl_xor(s, 1); s += __shfl_xor(s, 2);
            if (q == 0) {
                s += (col < 80) ? pjb[col] : gtb[0];
                if (col < 80) out[((size_t)b * NMEL + col) * TOUT + t] = s;
                else          out[(size_t)NB * NMEL * TOUT + (size_t)b * TOUT + t] = s;
            }
        }
    } else {
        int b = bid - 32;
        float* AH = ws + WS_AH + (size_t)b * NU;
        float* AC = ws + WS_AC + (size_t)b * NU;
        for (int u = tid; u < NU; u += 512) {
            float zi = abih[u]          + abhh[u];
            float zf = abih[NU + u]     + abhh[NU + u];
            float zg = abih[2 * NU + u] + abhh[2 * NU + u];
            float zo = abih[3 * NU + u] + abhh[3 * NU + u];
            for (int s = 0; s < 14; s++) {
                const float* z = ws + WS_ZA + ((size_t)s * NB + b) * NG;
                zi += z[u]; zf += z[NU + u]; zg += z[2 * NU + u]; zo += z[3 * NU + u];
            }
            float c = fsigm(zf) * AC[u] + fsigm(zi) * ftanh(zg);
            float h = fsigm(zo) * ftanh(c);
            AC[u] = c; AH[u] = h; sm[u] = h;
        }
        __syncthreads();
        int a = tid >> 2, q = tid & 3;
        if (a < NATT) {
            const float* qr = qw + (size_t)a * NU + q * 256;
            const float* h4 = sm + q * 256;
            float s = 0.f;
#pragma unroll
            for (int k4 = 0; k4 < 64; k4++) {
                float4 hv = *(const float4*)(h4 + k4 * 4);
                float4 wv = *(const float4*)(qr + k4 * 4);
                s = fmaf(hv.x, wv.x, s); s = fmaf(hv.y, wv.y, s);
                s = fmaf(hv.z, wv.z, s); s = fmaf(hv.w, wv.w, s);
            }
            s += __shfl_xor(s, 1); s += __shfl_xor(s, 2);
            if (q == 0) ws[WS_PQ + b * NATT + a] = s;
        }
    }
}

extern "C" void kernel_launch(void* const* d_in, const int* in_sizes, int n_in,
                              void* d_out, int out_size, void* d_ws, size_t ws_size,
                              hipStream_t stream) {
    const float* memory = (const float*)d_in[0];
    const float* dec    = (const float*)d_in[1];
    const int*   mlen   = (const int*)d_in[2];
    const float* pw1    = (const float*)d_in[3];
    const float* pw2    = (const float*)d_in[4];
    const float* awih   = (const float*)d_in[5];
    const float* awhh   = (const float*)d_in[6];
    const float* abih   = (const float*)d_in[7];
    const float* abhh   = (const float*)d_in[8];
    const float* qw     = (const float*)d_in[9];
    const float* mw     = (const float*)d_in[10];
    const float* vw     = (const float*)d_in[11];
    const float* wc     = (const float*)d_in[12];
    const float* ldw    = (const float*)d_in[13];
    const float* dwih   = (const float*)d_in[14];
    const float* dwhh   = (const float*)d_in[15];
    const float* dbih   = (const float*)d_in[16];
    const float* dbhh   = (const float*)d_in[17];
    const float* pjw    = (const float*)d_in[18];
    const float* pjb    = (const float*)d_in[19];
    const float* gtw    = (const float*)d_in[20];
    const float* gtb    = (const float*)d_in[21];
    float* ws  = (float*)d_ws;
    float* out = (float*)d_out;
    float* out_align = out + OUT_ALIGN;

    // zero recurrent state + pre row 512 (tail pad)
    hipMemsetAsync(ws, 0, WS_STATE_ZERO_BYTES, stream);
    hipMemsetAsync(ws + WS_PRE + (size_t)512 * NB * NPRE, 0, (size_t)NB * NPRE * 4, stream);

    prenet1_kernel<<<TOUT, 256, 0, stream>>>(dec, pw1, ws + WS_PRE);
    prenet2_kernel<<<TOUT, 256, 0, stream>>>(pw2, ws + WS_PRE);
    pm_kernel<<<dim3(TIN / 4, NB), 128, 0, stream>>>(memory, mw, ws + WS_PM);

    // prologue: za(0) (AH/ACTX zeroed), then agates+pq(0)
    z_fused_kernel<<<dim3(16, 14), 256, 0, stream>>>(
        dwih, dwhh, awih, awhh, ws, ws + WS_PRE, ws + WS_ZD, ws + WS_ZA, 20);
    gates_kernel<<<64, 512, 0, stream>>>(abih, abhh, qw, dbih, dbhh, pjw, pjb,
                                         gtw, gtb, ws, out, -1);

    for (int t = 0; t < TOUT; ++t) {
        energies_kernel<<<dim3(16, NB), 128, 0, stream>>>(
            ws + WS_PM, wc, ldw, vw, mlen,
            ws + WS_AW, ws + WS_AWCUM, ws + WS_PQ, ws + WS_E);
        softmax_ctx_kernel<<<dim3(8, NB), 256, 0, stream>>>(
            memory, ws + WS_E, ws + WS_AW, ws + WS_AWCUM, ws + WS_ACTX, out_align, t);
        z_fused_kernel<<<dim3(16, 34), 256, 0, stream>>>(
            dwih, dwhh, awih, awhh, ws,
            ws + WS_PRE + (size_t)(t + 1) * NB * NPRE,
            ws + WS_ZD, ws + WS_ZA, 0);
        gates_kernel<<<64, 512, 0, stream>>>(abih, abhh, qw, dbih, dbhh, pjw, pjb,
                                             gtw, gtb, ws, out, t);
    }
}